// Round 3
// baseline (836.254 us; speedup 1.0000x reference)
//
#include <hip/hip_runtime.h>
#include <hip/hip_cooperative_groups.h>
#include <math.h>

namespace cg = cooperative_groups;

#define NBR    4        // NUM_BRANCHES
#define REP    1024     // REP_DIM
#define FD     128      // FEAT_DIM
#define NDATA  100000
#define KP1    4097     // NCE_K + 1
#define BN     128      // BATCH
#define MPN    0.04096f // m * Pn = 4096 / 100000
#define EPS_C  1e-7f
#define TINV   (1.0f / 0.07f)
#define NSLOT  64       // atomic slots (cachelines) for partial sums
#define TREFS  (BN * KP1)   // 524,416 total (b,k) refs

typedef unsigned int   uint4e   __attribute__((ext_vector_type(4)));
typedef unsigned short ushort4e __attribute__((ext_vector_type(4)));
typedef _Float16       half2e   __attribute__((ext_vector_type(2)));
typedef float          floatx4  __attribute__((ext_vector_type(4)));

// ---------------------------------------------------------------------------
// fp16 / bf16 helpers
// ---------------------------------------------------------------------------
static __device__ __forceinline__ unsigned short f2h(float f) {
    union { _Float16 h; unsigned short u; } c; c.h = (_Float16)f; return c.u;
}
static __device__ __forceinline__ float h_lo(unsigned int u) {
    union { unsigned int u; _Float16 h[2]; } c; c.u = u; return (float)c.h[0];
}
static __device__ __forceinline__ float h_hi(unsigned int u) {
    union { unsigned int u; _Float16 h[2]; } c; c.u = u; return (float)c.h[1];
}
static __device__ __forceinline__ half2e u2h2(unsigned int u) {
    union { unsigned int u; half2e h; } c; c.u = u; return c.h;
}
static __device__ __forceinline__ unsigned short f2bf(float f) {
    union { float f; unsigned int u; } c; c.f = f;
    unsigned int u = c.u;
    u += 0x7fffu + ((u >> 16) & 1u);
    return (unsigned short)(u >> 16);
}
static __device__ __forceinline__ float bf2f(unsigned short h) {
    union { unsigned int u; float f; } c; c.u = ((unsigned int)h) << 16;
    return c.f;
}

// ---------------------------------------------------------------------------
// shared: pass-2 per-item accumulation (16 log terms from 32B of f16 expS)
// ---------------------------------------------------------------------------
static __device__ __forceinline__ void acc_words(const uint4& p0, const uint4& p1,
                                                 const float* __restrict__ s_zinv,
                                                 float* __restrict__ acc, bool pos) {
    unsigned int wds[8] = {p0.x, p0.y, p0.z, p0.w, p1.x, p1.y, p1.z, p1.w};
#pragma unroll
    for (int w = 0; w < 8; ++w) {
        float v0 = h_lo(wds[w]) * s_zinv[2*w];
        float v1 = h_hi(wds[w]) * s_zinv[2*w+1];
        if (pos) {
            acc[2*w]   += -__logf(1.f + (MPN + EPS_C) / v0);
            acc[2*w+1] += -__logf(1.f + (MPN + EPS_C) / v1);
        } else {
            acc[2*w]   += -__logf(1.f + (v0 + EPS_C) * (1.f / MPN));
            acc[2*w+1] += -__logf(1.f + (v1 + EPS_C) * (1.f / MPN));
        }
    }
}

// ===========================================================================
// FUSED COOPERATIVE MEGA-KERNEL
// Phases (grid.sync between each):
//  P0 zero counts/fill/cursor/Zsl/out
//  P1 feat (blocks < F) || hist (blocks >= F)
//  P3 assign (block scan + atomic cursor)
//  P4 scatter -> inv64 bucket-ordered ref list
//  P5 pass1: stream mem once, fdot2 + folded butterfly + exp + expS store
//  P6 pass2: stream expS, 16 log-sums, masked atomicAdd into out
// e is packed f16 [b][d0blk(16)][i(4)][8] so one item's 4 e-fragments per lane
// are a single contiguous 64B line.
// ===========================================================================
__global__ __launch_bounds__(256, 4)
void k_all(const float* __restrict__ e0, const float* __restrict__ e1,
           const float* __restrict__ e2, const float* __restrict__ e3,
           const float* __restrict__ W, const float* __restrict__ bias,
           const float* __restrict__ mem, const int* __restrict__ cidx,
           ushort* __restrict__ eh2, int* __restrict__ counts,
           int* __restrict__ start, int* __restrict__ fill,
           int* __restrict__ cursor, unsigned long long* __restrict__ inv64,
           ushort* __restrict__ expS, float* __restrict__ Zsl,
           float* __restrict__ out) {
    cg::grid_group grid = cg::this_grid();
    const int tid = threadIdx.x;

    __shared__ float s_emb[REP];       // P1 feat
    __shared__ float s_part[256];      // P1 feat
    __shared__ float s_sq[FD];         // P1 feat
    __shared__ int   s_scan[256];      // P3 assign
    __shared__ int   s_base;           // P3 assign
    __shared__ float s_z[4][16];       // P5
    __shared__ float s_zinv[16];       // P6
    __shared__ float s_a[4][16];       // P6

    // ---------------- P0: zero ----------------
    {
        const int NT = gridDim.x * 256;
        for (int t = blockIdx.x * 256 + tid; t < NDATA; t += NT) {
            counts[t] = 0; fill[t] = 0;
        }
        for (int t = blockIdx.x * 256 + tid; t < NSLOT * 16; t += NT) Zsl[t] = 0.f;
        if (blockIdx.x == 0 && tid == 0) { cursor[0] = 0; out[0] = 0.f; }
    }
    grid.sync();

    // ---------------- P1: feat || hist ----------------
    {
        const int F = (gridDim.x + 1) >> 1;
        if ((int)blockIdx.x < F) {
            for (int u = blockIdx.x; u < NBR * BN; u += F) {
                const int r = u >> 7;
                const int b = u & 127;
                const float* emb = (r == 0 ? e0 : r == 1 ? e1 : r == 2 ? e2 : e3)
                                   + (size_t)b * REP;
                for (int t = tid; t < REP; t += 256) s_emb[t] = emb[t];
                __syncthreads();
                const int d  = tid & 127;
                const int kh = tid >> 7;
                const float4* wrow = (const float4*)(W + ((size_t)r * FD + d) * REP)
                                     + kh * 128;
                const float* se = s_emb + (kh << 9);
                float a = 0.f;
#pragma unroll 4
                for (int c = 0; c < 128; ++c) {
                    float4 v = wrow[c];
                    a += v.x * se[4*c+0] + v.y * se[4*c+1]
                       + v.z * se[4*c+2] + v.w * se[4*c+3];
                }
                s_part[tid] = a;
                __syncthreads();
                float h = 0.f;
                if (kh == 0) {
                    h = s_part[d] + s_part[128 + d] + bias[r * FD + d];
                    s_sq[d] = h * h;
                }
                __syncthreads();
                for (int off = 64; off > 0; off >>= 1) {
                    if (tid < off) s_sq[tid] += s_sq[tid + off];
                    __syncthreads();
                }
                float nrm = sqrtf(s_sq[0]);
                if (kh == 0) {
                    // layout [b][d>>3][i][d&7]
                    eh2[((size_t)(b * 16 + (d >> 3)) * 4 + r) * 8 + (d & 7)]
                        = f2h(h / nrm);
                }
                __syncthreads();
            }
        } else {
            const int NT = (gridDim.x - F) * 256;
            for (int t = ((int)blockIdx.x - F) * 256 + tid; t < TREFS; t += NT)
                atomicAdd(&counts[cidx[t]], 1);
        }
    }
    grid.sync();

    // ---------------- P3: assign (scan + atomic cursor) ----------------
    {
        const int NCH = (NDATA + 255) / 256;   // 391
        for (int ch = blockIdx.x; ch < NCH; ch += gridDim.x) {
            const int n = ch * 256 + tid;
            int c = (n < NDATA) ? counts[n] : 0;
            s_scan[tid] = c;
            __syncthreads();
#pragma unroll
            for (int off = 1; off < 256; off <<= 1) {
                int v = (tid >= off) ? s_scan[tid - off] : 0;
                __syncthreads();
                s_scan[tid] += v;
                __syncthreads();
            }
            if (tid == 255) s_base = atomicAdd(cursor, s_scan[255]);
            __syncthreads();
            if (n < NDATA) start[n] = s_base + s_scan[tid] - c;
            __syncthreads();
        }
    }
    grid.sync();

    // ---------------- P4: scatter ----------------
    {
        const int NT = gridDim.x * 256;
        for (int t = blockIdx.x * 256 + tid; t < TREFS; t += NT) {
            const int n = cidx[t];
            const int b = t / KP1;
            const int k = t - b * KP1;
            const int pos = atomicAdd(&fill[n], 1);
            inv64[(size_t)start[n] + pos] =
                ((unsigned long long)(unsigned int)n << 20) |
                ((unsigned long long)(unsigned int)b << 13) |
                (unsigned long long)(unsigned int)k;
        }
    }
    grid.sync();

    // ---------------- P5: pass1 ----------------
    {
        const int lane = tid & 63;
        const int wv   = tid >> 6;
        const int g    = ((int)blockIdx.x << 2) + wv;
        const int NW   = (int)gridDim.x << 2;
        const int PER  = TREFS / NW;
        const int REM  = TREFS - PER * NW;
        const int base = g * PER + (g < REM ? g : REM);
        const int end  = base + PER + (g < REM ? 1 : 0);
        const int l4   = lane & 15;
        const int jj   = lane >> 4;
        const bool f3  = (l4 & 8) != 0;
        const bool fl2 = (l4 & 4) != 0;

        const float* mrow_base = mem + (size_t)jj * (NDATA * FD) + l4 * 8;
        const uint4* e4 = (const uint4*)eh2;

        float z = 0.f;
        int n_prev = -1;
        half2e mh0 = half2e{(_Float16)0.f, (_Float16)0.f};
        half2e mh1 = mh0, mh2 = mh0, mh3 = mh0;

        auto proc = [&](unsigned long long v, const uint4& q0, const uint4& q1,
                        const uint4& q2, const uint4& q3) {
            const int n = (int)(v >> 20);
            const unsigned int bk = (unsigned int)v & 0xFFFFFu;
            const int b = (int)(bk >> 13);
            const int k = (int)(bk & 8191u);
            if (n != n_prev) {   // wave-uniform (item-level)
                const floatx4* mp = (const floatx4*)(mrow_base + (size_t)n * FD);
                floatx4 r0 = __builtin_nontemporal_load(mp);
                floatx4 r1 = __builtin_nontemporal_load(mp + 1);
                mh0 = half2e{(_Float16)r0.x, (_Float16)r0.y};
                mh1 = half2e{(_Float16)r0.z, (_Float16)r0.w};
                mh2 = half2e{(_Float16)r1.x, (_Float16)r1.y};
                mh3 = half2e{(_Float16)r1.z, (_Float16)r1.w};
                n_prev = n;
            }
            float a0 = 0.f, a1 = 0.f, a2 = 0.f, a3 = 0.f;
            a0 = __builtin_amdgcn_fdot2(mh0, u2h2(q0.x), a0, false);
            a0 = __builtin_amdgcn_fdot2(mh1, u2h2(q0.y), a0, false);
            a0 = __builtin_amdgcn_fdot2(mh2, u2h2(q0.z), a0, false);
            a0 = __builtin_amdgcn_fdot2(mh3, u2h2(q0.w), a0, false);
            a1 = __builtin_amdgcn_fdot2(mh0, u2h2(q1.x), a1, false);
            a1 = __builtin_amdgcn_fdot2(mh1, u2h2(q1.y), a1, false);
            a1 = __builtin_amdgcn_fdot2(mh2, u2h2(q1.z), a1, false);
            a1 = __builtin_amdgcn_fdot2(mh3, u2h2(q1.w), a1, false);
            a2 = __builtin_amdgcn_fdot2(mh0, u2h2(q2.x), a2, false);
            a2 = __builtin_amdgcn_fdot2(mh1, u2h2(q2.y), a2, false);
            a2 = __builtin_amdgcn_fdot2(mh2, u2h2(q2.z), a2, false);
            a2 = __builtin_amdgcn_fdot2(mh3, u2h2(q2.w), a2, false);
            a3 = __builtin_amdgcn_fdot2(mh0, u2h2(q3.x), a3, false);
            a3 = __builtin_amdgcn_fdot2(mh1, u2h2(q3.y), a3, false);
            a3 = __builtin_amdgcn_fdot2(mh2, u2h2(q3.z), a3, false);
            a3 = __builtin_amdgcn_fdot2(mh3, u2h2(q3.w), a3, false);
            // folded butterfly within 16-lane j-group
            float t0 = __shfl_xor(f3 ? a0 : a2, 8, 64);
            float t1 = __shfl_xor(f3 ? a1 : a3, 8, 64);
            float c0 = (f3 ? a2 : a0) + t0;
            float c1 = (f3 ? a3 : a1) + t1;
            float t2 = __shfl_xor(fl2 ? c0 : c1, 4, 64);
            float dd = (fl2 ? c1 : c0) + t2;
            dd += __shfl_xor(dd, 2, 64);
            dd += __shfl_xor(dd, 1, 64);
            float x = __expf(dd * TINV);
            z += x;
            if ((lane & 3) == 0)
                expS[((size_t)b * KP1 + k) * 16 + (lane >> 2)] = f2h(x);
        };

        uint4 qA0, qA1, qA2, qA3, qB0, qB1, qB2, qB3;
        unsigned long long v0 = inv64[base];
        unsigned long long v1 = (base + 1 < end) ? inv64[base + 1] : v0;
        {
            const uint4* p = e4 + ((size_t)(((unsigned)v0 & 0xFFFFFu) >> 13) * 16 + l4) * 4;
            qA0 = p[0]; qA1 = p[1]; qA2 = p[2]; qA3 = p[3];
        }
        {
            const uint4* p = e4 + ((size_t)(((unsigned)v1 & 0xFFFFFu) >> 13) * 16 + l4) * 4;
            qB0 = p[0]; qB1 = p[1]; qB2 = p[2]; qB3 = p[3];
        }

        int c = base;
        for (; c + 1 < end; c += 2) {
            unsigned long long v2 = (c + 2 < end) ? inv64[c + 2] : v1;
            unsigned long long v3 = (c + 3 < end) ? inv64[c + 3] : v2;
            proc(v0, qA0, qA1, qA2, qA3);
            {   // refill A for item c+2 (consumed next iteration)
                const uint4* p = e4 + ((size_t)(((unsigned)v2 & 0xFFFFFu) >> 13) * 16 + l4) * 4;
                qA0 = p[0]; qA1 = p[1]; qA2 = p[2]; qA3 = p[3];
            }
            proc(v1, qB0, qB1, qB2, qB3);
            {   // refill B for item c+3
                const uint4* p = e4 + ((size_t)(((unsigned)v3 & 0xFFFFFu) >> 13) * 16 + l4) * 4;
                qB0 = p[0]; qB1 = p[1]; qB2 = p[2]; qB3 = p[3];
            }
            v0 = v2; v1 = v3;
        }
        if (c < end) proc(v0, qA0, qA1, qA2, qA3);

        // cross-wave LDS reduce -> one coalesced 16-lane atomic per block
        const int i = ((l4 >> 3) << 1) | ((l4 >> 2) & 1);
        if ((lane & 3) == 0) s_z[wv][i * 4 + jj] = z;
        __syncthreads();
        if (tid < 16) {
            float vv = s_z[0][tid] + s_z[1][tid] + s_z[2][tid] + s_z[3][tid];
            const int slot = blockIdx.x & (NSLOT - 1);
            atomicAdd(&Zsl[slot * 16 + tid], vv);
        }
    }
    grid.sync();

    // ---------------- P6: pass2 + masked final atomic ----------------
    {
        if (tid < 16) {
            // expS half t: j = t>>2, i = t&3 ; Zsl component layout is i*4+j
            const int comp = ((tid & 3) << 2) | (tid >> 2);
            float s = 0.f;
            for (int sl = 0; sl < NSLOT; ++sl) s += Zsl[sl * 16 + comp];
            float Z = s * (float)((double)NDATA / ((double)BN * (double)KP1));
            s_zinv[tid] = 1.0f / Z;
        }
        __syncthreads();

        const uint4* esu = (const uint4*)expS;
        float acc[16];
#pragma unroll
        for (int t = 0; t < 16; ++t) acc[t] = 0.f;

        const int NT = gridDim.x * 256;
        for (int t = blockIdx.x * 256 + tid; t < TREFS; t += NT) {
            const int b = t / KP1;
            const int k = t - b * KP1;
            uint4 p0 = esu[(size_t)t * 2];
            uint4 p1 = esu[(size_t)t * 2 + 1];
            acc_words(p0, p1, s_zinv, acc, k == 0);
        }

#pragma unroll
        for (int t = 0; t < 16; ++t) {
#pragma unroll
            for (int off = 32; off > 0; off >>= 1)
                acc[t] += __shfl_down(acc[t], off, 64);
        }
        const int wv = tid >> 6;
        if ((tid & 63) == 0) {
#pragma unroll
            for (int t = 0; t < 16; ++t) s_a[wv][t] = acc[t];
        }
        __syncthreads();
        if (tid < 16) {
            float v = s_a[0][tid] + s_a[1][tid] + s_a[2][tid] + s_a[3][tid];
            const int jjj = tid >> 2, iii = tid & 3;
            v = (iii != jjj) ? v : 0.f;
            v += __shfl_down(v, 8, 64);
            v += __shfl_down(v, 4, 64);
            v += __shfl_down(v, 2, 64);
            v += __shfl_down(v, 1, 64);
            if (tid == 0) atomicAdd(out, -v / (float)BN);
        }
    }
}

// ===========================================================================
// Round-2 multi-kernel path (fallback if cooperative launch unavailable)
// ===========================================================================
__global__ void k_feat(const float* __restrict__ e0, const float* __restrict__ e1,
                       const float* __restrict__ e2, const float* __restrict__ e3,
                       const float* __restrict__ W, const float* __restrict__ bias,
                       float* __restrict__ e_out, ushort* __restrict__ eh16) {
    const int r = blockIdx.x;
    const int b = blockIdx.y;
    const float* emb = (r == 0 ? e0 : r == 1 ? e1 : r == 2 ? e2 : e3) + (size_t)b * REP;

    __shared__ float s_emb[REP];
    for (int i = threadIdx.x; i < REP; i += blockDim.x) s_emb[i] = emb[i];
    __syncthreads();

    const int d = threadIdx.x;
    const float4* wrow = (const float4*)(W + ((size_t)r * FD + d) * REP);
    float acc = 0.f;
#pragma unroll 8
    for (int c = 0; c < REP / 4; ++c) {
        float4 v = wrow[c];
        acc += v.x * s_emb[4*c+0] + v.y * s_emb[4*c+1]
             + v.z * s_emb[4*c+2] + v.w * s_emb[4*c+3];
    }
    float h = acc + bias[r * FD + d];

    __shared__ float red[FD];
    red[d] = h * h;
    __syncthreads();
    for (int off = FD / 2; off > 0; off >>= 1) {
        if (d < off) red[d] += red[d + off];
        __syncthreads();
    }
    float nrm = sqrtf(red[0]);
    float val = h / nrm;
    e_out[((size_t)r * BN + b) * FD + d] = val;
    if (eh16) eh16[((size_t)r * BN + b) * FD + d] = f2h(val);
}

__global__ void k_hist(const int* __restrict__ cidx, int* __restrict__ counts) {
    const int k = blockIdx.x * 256 + threadIdx.x;
    if (k >= KP1) return;
    const int b = blockIdx.y;
    atomicAdd(&counts[cidx[(size_t)b * KP1 + k]], 1);
}

__global__ void k_assign(const int* __restrict__ counts, int* __restrict__ start,
                         int* __restrict__ cursor) {
    __shared__ int s[256];
    __shared__ int sbase;
    const int tid = threadIdx.x;
    const int n = blockIdx.x * 256 + tid;
    int c = (n < NDATA) ? counts[n] : 0;
    s[tid] = c;
    __syncthreads();
#pragma unroll
    for (int off = 1; off < 256; off <<= 1) {
        int v = (tid >= off) ? s[tid - off] : 0;
        __syncthreads();
        s[tid] += v;
        __syncthreads();
    }
    if (tid == 255) sbase = atomicAdd(cursor, s[255]);
    __syncthreads();
    if (n < NDATA) start[n] = sbase + s[tid] - c;
}

__global__ void k_scatter(const int* __restrict__ cidx, const int* __restrict__ start,
                          int* __restrict__ fill, unsigned long long* __restrict__ inv64) {
    const int k = blockIdx.x * 256 + threadIdx.x;
    if (k >= KP1) return;
    const int b = blockIdx.y;
    const int n = cidx[(size_t)b * KP1 + k];
    const int pos = atomicAdd(&fill[n], 1);
    inv64[(size_t)start[n] + pos] =
        ((unsigned long long)(unsigned int)n << 20) |
        ((unsigned long long)(unsigned int)b << 13) |
        (unsigned long long)(unsigned int)k;
}

__global__ __launch_bounds__(256)
void k_pass1i(const float* __restrict__ mem, const ushort* __restrict__ eh16,
              const unsigned long long* __restrict__ inv64,
              float* __restrict__ Zsl, ushort* __restrict__ expS) {
    const int lane = threadIdx.x & 63;
    const int w    = threadIdx.x >> 6;
    const int g    = (blockIdx.x << 2) + w;
    const int l4   = lane & 15;
    const int jj   = lane >> 4;
    const int d0   = l4 * 8;
    const bool b3  = (l4 & 8) != 0;
    const bool b2  = (l4 & 4) != 0;

    const int base = g * 64 + (g < 128 ? g : 128);
    const int end  = base + 64 + (g < 128 ? 1 : 0);

    const float* mrow_base = mem + (size_t)jj * NDATA * FD + d0;
    const ushort* eb_base  = eh16 + d0;

    float z = 0.f;
    int n_prev = -1;
    half2e mh[4];
    mh[0] = half2e{(_Float16)0.f, (_Float16)0.f};
    mh[1] = mh[0]; mh[2] = mh[0]; mh[3] = mh[0];

    unsigned long long vnext = inv64[base];
    for (int c = base; c < end; ++c) {
        const unsigned long long v = vnext;
        if (c + 1 < end) vnext = inv64[c + 1];
        const int n = (int)(v >> 20);
        const unsigned int bk = (unsigned int)v & 0xFFFFFu;
        const int b = (int)(bk >> 13);
        const int k = (int)(bk & 8191u);

        const ushort* eb = eb_base + (size_t)b * FD;
        uint4 ev0 = *(const uint4*)(eb);
        uint4 ev1 = *(const uint4*)(eb + (size_t)1 * BN * FD);
        uint4 ev2 = *(const uint4*)(eb + (size_t)2 * BN * FD);
        uint4 ev3 = *(const uint4*)(eb + (size_t)3 * BN * FD);

        if (n != n_prev) {
            const floatx4* mp = (const floatx4*)(mrow_base + (size_t)n * FD);
            floatx4 v0 = __builtin_nontemporal_load(mp);
            floatx4 v1 = __builtin_nontemporal_load(mp + 1);
            mh[0] = half2e{(_Float16)v0.x, (_Float16)v0.y};
            mh[1] = half2e{(_Float16)v0.z, (_Float16)v0.w};
            mh[2] = half2e{(_Float16)v1.x, (_Float16)v1.y};
            mh[3] = half2e{(_Float16)v1.z, (_Float16)v1.w};
            n_prev = n;
        }

        float a0 = 0.f, a1 = 0.f, a2 = 0.f, a3 = 0.f;
        a0 = __builtin_amdgcn_fdot2(mh[0], u2h2(ev0.x), a0, false);
        a0 = __builtin_amdgcn_fdot2(mh[1], u2h2(ev0.y), a0, false);
        a0 = __builtin_amdgcn_fdot2(mh[2], u2h2(ev0.z), a0, false);
        a0 = __builtin_amdgcn_fdot2(mh[3], u2h2(ev0.w), a0, false);
        a1 = __builtin_amdgcn_fdot2(mh[0], u2h2(ev1.x), a1, false);
        a1 = __builtin_amdgcn_fdot2(mh[1], u2h2(ev1.y), a1, false);
        a1 = __builtin_amdgcn_fdot2(mh[2], u2h2(ev1.z), a1, false);
        a1 = __builtin_amdgcn_fdot2(mh[3], u2h2(ev1.w), a1, false);
        a2 = __builtin_amdgcn_fdot2(mh[0], u2h2(ev2.x), a2, false);
        a2 = __builtin_amdgcn_fdot2(mh[1], u2h2(ev2.y), a2, false);
        a2 = __builtin_amdgcn_fdot2(mh[2], u2h2(ev2.z), a2, false);
        a2 = __builtin_amdgcn_fdot2(mh[3], u2h2(ev2.w), a2, false);
        a3 = __builtin_amdgcn_fdot2(mh[0], u2h2(ev3.x), a3, false);
        a3 = __builtin_amdgcn_fdot2(mh[1], u2h2(ev3.y), a3, false);
        a3 = __builtin_amdgcn_fdot2(mh[2], u2h2(ev3.z), a3, false);
        a3 = __builtin_amdgcn_fdot2(mh[3], u2h2(ev3.w), a3, false);

        float t0 = __shfl_xor(b3 ? a0 : a2, 8, 64);
        float t1 = __shfl_xor(b3 ? a1 : a3, 8, 64);
        float c0 = (b3 ? a2 : a0) + t0;
        float c1 = (b3 ? a3 : a1) + t1;
        float t2 = __shfl_xor(b2 ? c0 : c1, 4, 64);
        float d  = (b2 ? c1 : c0) + t2;
        d += __shfl_xor(d, 2, 64);
        d += __shfl_xor(d, 1, 64);
        float x = __expf(d * TINV);
        z += x;
        if ((lane & 3) == 0)
            expS[((size_t)b * KP1 + k) * 16 + (lane >> 2)] = f2h(x);
    }

    __shared__ float s_z[4][16];
    const int j = lane >> 4;
    const int i = ((l4 >> 3) << 1) | ((l4 >> 2) & 1);
    if ((lane & 3) == 0) s_z[w][i * 4 + j] = z;
    __syncthreads();
    if (threadIdx.x < 16) {
        float vv = s_z[0][threadIdx.x] + s_z[1][threadIdx.x]
                 + s_z[2][threadIdx.x] + s_z[3][threadIdx.x];
        const int slot = blockIdx.x & (NSLOT - 1);
        atomicAdd(&Zsl[slot * 16 + threadIdx.x], vv);
    }
}

__global__ void k_zred(const float* __restrict__ Zsl, float* __restrict__ Zsum) {
    if (threadIdx.x < 16) {
        float s = 0.f;
        for (int sl = 0; sl < NSLOT; ++sl) s += Zsl[sl * 16 + threadIdx.x];
        Zsum[threadIdx.x] = s;
    }
}

__global__ __launch_bounds__(256)
void k_pass2f(const uint4* __restrict__ expS, const float* __restrict__ Zsum,
              float* __restrict__ Asl) {
    const int b = blockIdx.y;

    __shared__ float s_zinv[16];
    if (threadIdx.x < 16) {
        int jj = threadIdx.x >> 2, ii = threadIdx.x & 3;
        float Z = Zsum[ii * 4 + jj] *
                  (float)((double)NDATA / ((double)BN * (double)KP1));
        s_zinv[threadIdx.x] = 1.0f / Z;
    }
    __syncthreads();

    const uint4* es = expS + (size_t)b * (KP1 * 2);
    const int base = threadIdx.x + blockIdx.x * 256;

    float acc[16];
#pragma unroll
    for (int t = 0; t < 16; ++t) acc[t] = 0.f;

#pragma unroll
    for (int it = 0; it < 2; ++it) {
        const int k = base + it * 2048;
        uint4 p0 = es[(size_t)k * 2];
        uint4 p1 = es[(size_t)k * 2 + 1];
        acc_words(p0, p1, s_zinv, acc, k == 0);
    }
    if (base == 0) {
        uint4 p0 = es[(size_t)4096 * 2];
        uint4 p1 = es[(size_t)4096 * 2 + 1];
        acc_words(p0, p1, s_zinv, acc, false);
    }

#pragma unroll
    for (int t = 0; t < 16; ++t) {
#pragma unroll
        for (int off = 32; off > 0; off >>= 1)
            acc[t] += __shfl_down(acc[t], off, 64);
    }
    __shared__ float s_a[4][16];
    const int w = threadIdx.x >> 6;
    if ((threadIdx.x & 63) == 0) {
#pragma unroll
        for (int t = 0; t < 16; ++t) s_a[w][t] = acc[t];
    }
    __syncthreads();
    if (threadIdx.x < 16) {
        float v = s_a[0][threadIdx.x] + s_a[1][threadIdx.x]
                + s_a[2][threadIdx.x] + s_a[3][threadIdx.x];
        const int slot = (blockIdx.y * gridDim.x + blockIdx.x) & (NSLOT - 1);
        atomicAdd(&Asl[slot * 16 + threadIdx.x], v);
    }
}

__global__ void k_final_slots(const float* __restrict__ Asl, float* __restrict__ out) {
    const int tid = threadIdx.x;
    const int comp = tid & 15;
    const int grp  = tid >> 4;
    float a = 0.f;
    for (int sl = grp; sl < NSLOT; sl += 16) a += Asl[sl * 16 + comp];
    const float m = ((comp >> 2) != (comp & 3)) ? 1.f : 0.f;
    __shared__ float s[256];
    s[tid] = a * m;
    __syncthreads();
    for (int off = 128; off > 0; off >>= 1) {
        if (tid < off) s[tid] += s[tid + off];
        __syncthreads();
    }
    if (tid == 0) out[0] = -s[0] / (float)BN;
}

// ---------------------------------------------------------------------------
// fp32 fallback pieces (only if workspace too small for the full path)
// ---------------------------------------------------------------------------
static __device__ __forceinline__ void dot4(const float4* __restrict__ row,
                                            const float* __restrict__ se,
                                            float& a0, float& a1, float& a2, float& a3) {
    a0 = a1 = a2 = a3 = 0.f;
#pragma unroll 8
    for (int c = 0; c < FD / 4; ++c) {
        float4 v = row[c];
        const int o = 4 * c;
        a0 += v.x * se[0*FD+o+0] + v.y * se[0*FD+o+1] + v.z * se[0*FD+o+2] + v.w * se[0*FD+o+3];
        a1 += v.x * se[1*FD+o+0] + v.y * se[1*FD+o+1] + v.z * se[1*FD+o+2] + v.w * se[1*FD+o+3];
        a2 += v.x * se[2*FD+o+0] + v.y * se[2*FD+o+1] + v.z * se[2*FD+o+2] + v.w * se[2*FD+o+3];
        a3 += v.x * se[3*FD+o+0] + v.y * se[3*FD+o+1] + v.z * se[3*FD+o+2] + v.w * se[3*FD+o+3];
    }
}

static __device__ __forceinline__ void block_reduce4(float z0, float z1, float z2,
                                                     float z3, float* dst, int j) {
    __shared__ float sred[256];
    float zs[NBR] = {z0, z1, z2, z3};
    for (int i = 0; i < NBR; ++i) {
        sred[threadIdx.x] = zs[i];
        __syncthreads();
        for (int off = 128; off > 0; off >>= 1) {
            if ((int)threadIdx.x < off) sred[threadIdx.x] += sred[threadIdx.x + off];
            __syncthreads();
        }
        if (threadIdx.x == 0) atomicAdd(&dst[i * NBR + j], sred[0]);
        __syncthreads();
    }
}

static __device__ __forceinline__ float term_of(float ex, float zinv, int k) {
    const float c = MPN + EPS_C;
    float v = ex * zinv;
    if (k == 0) return -__logf(1.0f + c / v);
    return -__logf(1.0f + (v + EPS_C) * (1.0f / MPN));
}

template <bool STORE>
__global__ void k_pass1_f32(const float* __restrict__ e, const float* __restrict__ memory,
                            const int* __restrict__ cidx,
                            float* __restrict__ Zsum, ushort4* __restrict__ expS) {
    const int j = blockIdx.z;
    const int b = blockIdx.y;

    __shared__ float s_e[NBR * FD];
    for (int t = threadIdx.x; t < NBR * FD; t += blockDim.x) {
        int i = t >> 7, d = t & (FD - 1);
        s_e[t] = e[((size_t)i * BN + b) * FD + d];
    }
    __syncthreads();

    const int* ci = cidx + (size_t)b * KP1;
    const float4* mem4 = (const float4*)(memory + (size_t)j * NDATA * FD);
    float z0 = 0.f, z1 = 0.f, z2 = 0.f, z3 = 0.f;

    for (int k = threadIdx.x + blockIdx.x * blockDim.x; k < KP1;
         k += blockDim.x * gridDim.x) {
        const int n = ci[k];
        const float4* row = mem4 + (size_t)n * (FD / 4);
        float a0, a1, a2, a3;
        dot4(row, s_e, a0, a1, a2, a3);
        float x0 = __expf(a0 * TINV);
        float x1 = __expf(a1 * TINV);
        float x2 = __expf(a2 * TINV);
        float x3 = __expf(a3 * TINV);
        z0 += x0; z1 += x1; z2 += x2; z3 += x3;
        if (STORE) {
            ushort4 st;
            st.x = f2bf(x0); st.y = f2bf(x1); st.z = f2bf(x2); st.w = f2bf(x3);
            expS[((size_t)j * BN + b) * KP1 + k] = st;
        }
    }
    block_reduce4(z0, z1, z2, z3, Zsum, j);
}

__global__ void k_pass2_stored(const ushort4* __restrict__ expS,
                               const float* __restrict__ Zsum,
                               float* __restrict__ accum) {
    const int j = blockIdx.z;
    const int b = blockIdx.y;

    __shared__ float s_zinv[NBR];
    if (threadIdx.x < NBR) {
        float Z = Zsum[threadIdx.x * NBR + j] *
                  (float)((double)NDATA / ((double)BN * (double)KP1));
        s_zinv[threadIdx.x] = 1.0f / Z;
    }
    __syncthreads();

    const ushort4* es = expS + ((size_t)j * BN + b) * KP1;
    float a0 = 0.f, a1 = 0.f, a2 = 0.f, a3 = 0.f;

    for (int k = threadIdx.x + blockIdx.x * blockDim.x; k < KP1;
         k += blockDim.x * gridDim.x) {
        ushort4 v = es[k];
        a0 += term_of(bf2f(v.x), s_zinv[0], k);
        a1 += term_of(bf2f(v.y), s_zinv[1], k);
        a2 += term_of(bf2f(v.z), s_zinv[2], k);
        a3 += term_of(bf2f(v.w), s_zinv[3], k);
    }
    block_reduce4(a0, a1, a2, a3, accum, j);
}

__global__ void k_pass2_regather(const float* __restrict__ e, const float* __restrict__ memory,
                                 const int* __restrict__ cidx,
                                 const float* __restrict__ Zsum, float* __restrict__ accum) {
    const int j = blockIdx.z;
    const int b = blockIdx.y;

    __shared__ float s_e[NBR * FD];
    __shared__ float s_zinv[NBR];
    for (int t = threadIdx.x; t < NBR * FD; t += blockDim.x) {
        int i = t >> 7, d = t & (FD - 1);
        s_e[t] = e[((size_t)i * BN + b) * FD + d];
    }
    if (threadIdx.x < NBR) {
        float Z = Zsum[threadIdx.x * NBR + j] *
                  (float)((double)NDATA / ((double)BN * (double)KP1));
        s_zinv[threadIdx.x] = 1.0f / Z;
    }
    __syncthreads();

    const int* ci = cidx + (size_t)b * KP1;
    const float4* mem4 = (const float4*)(memory + (size_t)j * NDATA * FD);
    float a0s = 0.f, a1s = 0.f, a2s = 0.f, a3s = 0.f;

    for (int k = threadIdx.x + blockIdx.x * blockDim.x; k < KP1;
         k += blockDim.x * gridDim.x) {
        const int n = ci[k];
        const float4* row = mem4 + (size_t)n * (FD / 4);
        float a0, a1, a2, a3;
        dot4(row, s_e, a0, a1, a2, a3);
        a0s += term_of(__expf(a0 * TINV), s_zinv[0], k);
        a1s += term_of(__expf(a1 * TINV), s_zinv[1], k);
        a2s += term_of(__expf(a2 * TINV), s_zinv[2], k);
        a3s += term_of(__expf(a3 * TINV), s_zinv[3], k);
    }
    block_reduce4(a0s, a1s, a2s, a3s, accum, j);
}

__global__ void k_init(float* __restrict__ p, int n) {
    int i = blockIdx.x * blockDim.x + threadIdx.x;
    if (i < n) p[i] = 0.f;
}

__global__ void k_final_legacy(const float* __restrict__ accum, float* __restrict__ out) {
    if (threadIdx.x == 0) {
        float s = 0.f;
        for (int i = 0; i < NBR; ++i)
            for (int j = 0; j < NBR; ++j)
                if (i != j) s += -accum[i * NBR + j] / (float)BN;
        out[0] = s;
    }
}

// ---------------------------------------------------------------------------
extern "C" void kernel_launch(void* const* d_in, const int* in_sizes, int n_in,
                              void* d_out, int out_size, void* d_ws, size_t ws_size,
                              hipStream_t stream) {
    const float* e0   = (const float*)d_in[0];
    const float* e1   = (const float*)d_in[1];
    const float* e2   = (const float*)d_in[2];
    const float* e3   = (const float*)d_in[3];
    const float* W    = (const float*)d_in[4];
    const float* bias = (const float*)d_in[5];
    const float* mem  = (const float*)d_in[6];
    const int*   cidx = (const int*)d_in[8];
    float* out = (float*)d_out;

    // ws (floats): e[65536] | Zsum[16] | accum[16] | Zsl[1024] | Asl[1024]
    // then (bytes, 16-aligned): eh16 | counts | fill | cursor | start | inv64 | expS | eh2
    float* ws    = (float*)d_ws;
    float* e     = ws;
    float* Zsum  = ws + 65536;
    float* accum = ws + 65552;
    float* Zsl   = ws + 65568;
    float* Asl   = ws + 66592;
    const size_t base_b   = (size_t)67616 * 4;
    const size_t eh16_b   = (size_t)NBR * BN * FD * 2;       // 131,072 B
    const size_t cnt_b    = (size_t)NDATA * 4;               // 400,000 B
    const size_t cur_b    = 16;
    const size_t inv_b    = (size_t)TREFS * 8;               // 4,195,328 B
    const size_t expS_b   = (size_t)BN * KP1 * 16 * 2;       // 16,781,312 B
    const size_t eh2_b    = (size_t)BN * 16 * 4 * 8 * 2;     // 131,072 B

    const size_t off_eh16   = base_b;
    const size_t off_counts = off_eh16 + eh16_b;
    const size_t off_fill   = off_counts + cnt_b;
    const size_t off_cursor = off_fill + cnt_b;
    const size_t off_start  = off_cursor + cur_b;
    const size_t off_inv    = off_start + cnt_b;
    const size_t off_expS   = off_inv + inv_b;
    const size_t off_eh2    = off_expS + expS_b;

    const size_t need_coop = off_eh2 + eh2_b;                // ~22.7 MB
    const size_t need_full = off_expS + expS_b;              // ~22.6 MB
    const size_t need_mid  = base_b + expS_b;                // ~17.05 MB

    // one-time: cooperative grid size (co-residency required)
    static int s_nblk = -1;
    if (s_nblk < 0) {
        int nb = 0;
        hipError_t oe = hipOccupancyMaxActiveBlocksPerMultiprocessor(
            &nb, (const void*)k_all, 256, 0);
        int dev = 0;
        hipGetDevice(&dev);
        hipDeviceProp_t prop;
        hipError_t pe = hipGetDeviceProperties(&prop, dev);
        if (oe == hipSuccess && pe == hipSuccess && nb > 0 &&
            prop.multiProcessorCount > 0) {
            long long t = (long long)nb * prop.multiProcessorCount;
            s_nblk = (int)(t > 2048 ? 2048 : t);
        } else {
            s_nblk = 0;
        }
    }

    bool done = false;
    if (ws_size >= need_coop && s_nblk >= 64) {
        ushort* eh2  = (ushort*)((char*)d_ws + off_eh2);
        int* counts  = (int*)((char*)d_ws + off_counts);
        int* start   = (int*)((char*)d_ws + off_start);
        int* fill    = (int*)((char*)d_ws + off_fill);
        int* cursor  = (int*)((char*)d_ws + off_cursor);
        unsigned long long* inv64 = (unsigned long long*)((char*)d_ws + off_inv);
        ushort* expS = (ushort*)((char*)d_ws + off_expS);

        void* kargs[] = {
            (void*)&e0, (void*)&e1, (void*)&e2, (void*)&e3,
            (void*)&W,  (void*)&bias, (void*)&mem, (void*)&cidx,
            (void*)&eh2, (void*)&counts, (void*)&start, (void*)&fill,
            (void*)&cursor, (void*)&inv64, (void*)&expS, (void*)&Zsl,
            (void*)&out
        };
        hipError_t le = hipLaunchCooperativeKernel(
            (const void*)k_all, dim3(s_nblk), dim3(256), kargs, 0, stream);
        if (le == hipSuccess) done = true;
        else s_nblk = 0;   // never retry cooperative on this device
    }

    if (!done && ws_size >= need_full) {
        ushort* eh16 = (ushort*)((char*)d_ws + off_eh16);
        int* counts  = (int*)((char*)d_ws + off_counts);
        int* fill    = (int*)((char*)d_ws + off_fill);
        int* cursor  = (int*)((char*)d_ws + off_cursor);
        int* start   = (int*)((char*)d_ws + off_start);
        unsigned long long* inv64 = (unsigned long long*)((char*)d_ws + off_inv);
        ushort* expS = (ushort*)((char*)d_ws + off_expS);

        k_init<<<9, 256, 0, stream>>>(Zsum, 2080);
        k_init<<<782, 256, 0, stream>>>((float*)counts, 200004);
        k_feat<<<dim3(NBR, BN), 128, 0, stream>>>(e0, e1, e2, e3, W, bias, e, eh16);
        k_hist<<<dim3(17, BN), 256, 0, stream>>>(cidx, counts);
        k_assign<<<391, 256, 0, stream>>>(counts, start, cursor);
        k_scatter<<<dim3(17, BN), 256, 0, stream>>>(cidx, start, fill, inv64);
        k_pass1i<<<2048, 256, 0, stream>>>(mem, eh16, inv64, Zsl, expS);
        k_zred<<<1, 64, 0, stream>>>(Zsl, Zsum);
        k_pass2f<<<dim3(8, BN), 256, 0, stream>>>((const uint4*)expS, Zsum, Asl);
        k_final_slots<<<1, 256, 0, stream>>>(Asl, out);
        done = true;
    }

    if (!done) {
        k_init<<<9, 256, 0, stream>>>(Zsum, 2080);
        k_feat<<<dim3(NBR, BN), 128, 0, stream>>>(e0, e1, e2, e3, W, bias, e, nullptr);
        if (ws_size >= need_mid) {
            ushort4* expS = (ushort4*)((char*)d_ws + base_b);
            k_pass1_f32<true><<<dim3(4, BN, NBR), 256, 0, stream>>>(e, mem, cidx, Zsum, expS);
            k_pass2_stored<<<dim3(4, BN, NBR), 256, 0, stream>>>(expS, Zsum, accum);
        } else {
            k_pass1_f32<false><<<dim3(4, BN, NBR), 256, 0, stream>>>(e, mem, cidx, Zsum, nullptr);
            k_pass2_regather<<<dim3(4, BN, NBR), 256, 0, stream>>>(e, mem, cidx, Zsum, accum);
        }
        k_final_legacy<<<1, 64, 0, stream>>>(accum, out);
    }
}

// Round 4
// 525.442 us; speedup vs baseline: 1.5915x; 1.5915x over previous
//
#include <hip/hip_runtime.h>
#include <math.h>

#define NBR    4        // NUM_BRANCHES
#define REP    1024     // REP_DIM
#define FD     128      // FEAT_DIM
#define NDATA  100000
#define KP1    4097     // NCE_K + 1
#define BN     128      // BATCH
#define MPN    0.04096f // m * Pn = 4096 / 100000
#define EPS_C  1e-7f
#define TINV   (1.0f / 0.07f)
#define NSLOT  64       // atomic slots for Z partial sums
#define TREFS  (BN * KP1)   // 524,416 total (b,k) refs

typedef _Float16 half2e  __attribute__((ext_vector_type(2)));
typedef float    floatx4 __attribute__((ext_vector_type(4)));

// ---------------------------------------------------------------------------
// fp16 / bf16 helpers
// ---------------------------------------------------------------------------
static __device__ __forceinline__ unsigned short f2h(float f) {
    union { _Float16 h; unsigned short u; } c; c.h = (_Float16)f; return c.u;
}
static __device__ __forceinline__ float h_lo(unsigned int u) {
    union { unsigned int u; _Float16 h[2]; } c; c.u = u; return (float)c.h[0];
}
static __device__ __forceinline__ float h_hi(unsigned int u) {
    union { unsigned int u; _Float16 h[2]; } c; c.u = u; return (float)c.h[1];
}
static __device__ __forceinline__ half2e u2h2(unsigned int u) {
    union { unsigned int u; half2e h; } c; c.u = u; return c.h;
}
static __device__ __forceinline__ unsigned short f2bf(float f) {
    union { float f; unsigned int u; } c; c.f = f;
    unsigned int u = c.u;
    u += 0x7fffu + ((u >> 16) & 1u);
    return (unsigned short)(u >> 16);
}
static __device__ __forceinline__ float bf2f(unsigned short h) {
    union { unsigned int u; float f; } c; c.u = ((unsigned int)h) << 16;
    return c.f;
}

// ---------------------------------------------------------------------------
// k_init2: zero counts+fill+cursor (contiguous 200004 ints), Zsl, out.
// grid 782, block 256.
// ---------------------------------------------------------------------------
__global__ void k_init2(int* __restrict__ cnts, float* __restrict__ Zsl,
                        float* __restrict__ out) {
    const int i = blockIdx.x * 256 + threadIdx.x;
    if (i < 200004) cnts[i] = 0;
    if (i < NSLOT * 16) Zsl[i] = 0.f;
    if (i == 0) out[0] = 0.f;
}

// ---------------------------------------------------------------------------
// k_fh: blocks [0,512): feat (one (r,b) item per block, 256 threads, K split
// in half) writing packed f16 e: eh2[b][d>>3][i][d&7].
// blocks [512,768): hist  counts[n] += 1 over all cidx entries.
// Independent work -> safe in one launch.
// ---------------------------------------------------------------------------
__global__ __launch_bounds__(256)
void k_fh(const float* __restrict__ e0, const float* __restrict__ e1,
          const float* __restrict__ e2, const float* __restrict__ e3,
          const float* __restrict__ W, const float* __restrict__ bias,
          const int* __restrict__ cidx,
          ushort* __restrict__ eh2, int* __restrict__ counts) {
    const int tid = threadIdx.x;
    if ((int)blockIdx.x < NBR * BN) {
        __shared__ float s_emb[REP];
        __shared__ float s_part[256];
        __shared__ float s_sq[FD];
        const int u = blockIdx.x;
        const int r = u >> 7;
        const int b = u & 127;
        const float* emb = (r == 0 ? e0 : r == 1 ? e1 : r == 2 ? e2 : e3)
                           + (size_t)b * REP;
        for (int t = tid; t < REP; t += 256) s_emb[t] = emb[t];
        __syncthreads();
        const int d  = tid & 127;
        const int kh = tid >> 7;
        const float4* wrow = (const float4*)(W + ((size_t)r * FD + d) * REP)
                             + kh * 128;
        const float* se = s_emb + (kh << 9);
        float a = 0.f;
#pragma unroll 4
        for (int c = 0; c < 128; ++c) {
            float4 v = wrow[c];
            a += v.x * se[4*c+0] + v.y * se[4*c+1]
               + v.z * se[4*c+2] + v.w * se[4*c+3];
        }
        s_part[tid] = a;
        __syncthreads();
        float h = 0.f;
        if (kh == 0) {
            h = s_part[d] + s_part[128 + d] + bias[r * FD + d];
            s_sq[d] = h * h;
        }
        __syncthreads();
        for (int off = 64; off > 0; off >>= 1) {
            if (tid < off) s_sq[tid] += s_sq[tid + off];
            __syncthreads();
        }
        float nrm = sqrtf(s_sq[0]);
        if (kh == 0) {
            eh2[((size_t)(b * 16 + (d >> 3)) * 4 + r) * 8 + (d & 7)]
                = f2h(h / nrm);
        }
    } else {
        const int NT = 256 * 256;
        for (int t = ((int)blockIdx.x - NBR * BN) * 256 + tid; t < TREFS; t += NT)
            atomicAdd(&counts[cidx[t]], 1);
    }
}

// ---------------------------------------------------------------------------
// k_assign: start[n] = running offset of bucket n (block scan + atomic cursor).
// Bucket order nondeterministic, contents contiguous. grid 391, block 256.
// ---------------------------------------------------------------------------
__global__ void k_assign(const int* __restrict__ counts, int* __restrict__ start,
                         int* __restrict__ cursor) {
    __shared__ int s[256];
    __shared__ int sbase;
    const int tid = threadIdx.x;
    const int n = blockIdx.x * 256 + tid;
    int c = (n < NDATA) ? counts[n] : 0;
    s[tid] = c;
    __syncthreads();
#pragma unroll
    for (int off = 1; off < 256; off <<= 1) {
        int v = (tid >= off) ? s[tid - off] : 0;
        __syncthreads();
        s[tid] += v;
        __syncthreads();
    }
    if (tid == 255) sbase = atomicAdd(cursor, s[255]);
    __syncthreads();
    if (n < NDATA) start[n] = sbase + s[tid] - c;
}

// ---------------------------------------------------------------------------
// k_scatter: inv64[start[n]+pos] = (n<<20)|(b<<13)|k; records posc[b] = c for
// the k==0 (positive) item of each b.  grid (17, BN), block 256.
// ---------------------------------------------------------------------------
__global__ void k_scatter(const int* __restrict__ cidx, const int* __restrict__ start,
                          int* __restrict__ fill, unsigned long long* __restrict__ inv64,
                          int* __restrict__ posc) {
    const int k = blockIdx.x * 256 + threadIdx.x;
    if (k >= KP1) return;
    const int b = blockIdx.y;
    const int n = cidx[(size_t)b * KP1 + k];
    const int pos = atomicAdd(&fill[n], 1);
    const int c = start[n] + pos;
    inv64[c] =
        ((unsigned long long)(unsigned int)n << 20) |
        ((unsigned long long)(unsigned int)b << 13) |
        (unsigned long long)(unsigned int)k;
    if (k == 0) posc[b] = c;
}

// ---------------------------------------------------------------------------
// k_pass1i v2: stream mem once in bucket order.
//  - e-fragments: one contiguous 64B line per lane (packed eh2), 2-deep
//    double-buffered prefetch (qA/qB).
//  - fp32 row: 1-run-ahead prefetch (pr regs) to hide the HBM row miss.
//  - expS stored at ref-order index c -> sequential 32B stores per wave.
// grid 2048, block 256 (8192 waves x 64 refs; first 128 waves take 65).
// ---------------------------------------------------------------------------
__global__ __launch_bounds__(256)
void k_pass1i(const float* __restrict__ mem, const ushort* __restrict__ eh2,
              const unsigned long long* __restrict__ inv64,
              float* __restrict__ Zsl, ushort* __restrict__ expS) {
    const int tid  = threadIdx.x;
    const int lane = tid & 63;
    const int wv   = tid >> 6;
    const int g    = ((int)blockIdx.x << 2) + wv;
    const int l4   = lane & 15;
    const int jj   = lane >> 4;
    const bool f3  = (l4 & 8) != 0;
    const bool fl2 = (l4 & 4) != 0;

    const int base = g * 64 + (g < 128 ? g : 128);
    const int end  = base + 64 + (g < 128 ? 1 : 0);

    const float* mrow = mem + (size_t)jj * (NDATA * FD) + l4 * 8;
    const uint4* e4   = (const uint4*)eh2;

    float z = 0.f;

    half2e mh0 = half2e{(_Float16)0.f, (_Float16)0.f};
    half2e mh1 = mh0, mh2 = mh0, mh3 = mh0;
    floatx4 pr0, pr1;
    int cur_n = -1;

    // item refs (prefetched 4 deep)
    unsigned long long v0 = inv64[base];
    unsigned long long v1 = inv64[base + 1];
    unsigned long long v2 = (base + 2 < end) ? inv64[base + 2] : v1;
    unsigned long long v3 = (base + 3 < end) ? inv64[base + 3] : v2;

    // e-line double buffer
    uint4 qA0, qA1, qA2, qA3, qB0, qB1, qB2, qB3;
    {
        const uint4* p = e4 + ((size_t)(((unsigned)v0 & 0xFFFFFu) >> 13) * 16 + l4) * 4;
        qA0 = p[0]; qA1 = p[1]; qA2 = p[2]; qA3 = p[3];
    }
    {
        const uint4* p = e4 + ((size_t)(((unsigned)v1 & 0xFFFFFu) >> 13) * 16 + l4) * 4;
        qB0 = p[0]; qB1 = p[1]; qB2 = p[2]; qB3 = p[3];
    }

    // row prefetch for first item
    int pend_n = (int)(v0 >> 20);
    {
        const floatx4* mp = (const floatx4*)(mrow + (size_t)pend_n * FD);
        pr0 = __builtin_nontemporal_load(mp);
        pr1 = __builtin_nontemporal_load(mp + 1);
    }

    auto cvt = [&]() {
        mh0 = half2e{(_Float16)pr0.x, (_Float16)pr0.y};
        mh1 = half2e{(_Float16)pr0.z, (_Float16)pr0.w};
        mh2 = half2e{(_Float16)pr1.x, (_Float16)pr1.y};
        mh3 = half2e{(_Float16)pr1.z, (_Float16)pr1.w};
    };
    auto ldrow = [&](int n) {
        const floatx4* mp = (const floatx4*)(mrow + (size_t)n * FD);
        pr0 = __builtin_nontemporal_load(mp);
        pr1 = __builtin_nontemporal_load(mp + 1);
        pend_n = n;
    };
    auto proc = [&](int cc, const uint4& q0, const uint4& q1,
                    const uint4& q2, const uint4& q3) {
        float a0 = 0.f, a1 = 0.f, a2 = 0.f, a3 = 0.f;
        a0 = __builtin_amdgcn_fdot2(mh0, u2h2(q0.x), a0, false);
        a0 = __builtin_amdgcn_fdot2(mh1, u2h2(q0.y), a0, false);
        a0 = __builtin_amdgcn_fdot2(mh2, u2h2(q0.z), a0, false);
        a0 = __builtin_amdgcn_fdot2(mh3, u2h2(q0.w), a0, false);
        a1 = __builtin_amdgcn_fdot2(mh0, u2h2(q1.x), a1, false);
        a1 = __builtin_amdgcn_fdot2(mh1, u2h2(q1.y), a1, false);
        a1 = __builtin_amdgcn_fdot2(mh2, u2h2(q1.z), a1, false);
        a1 = __builtin_amdgcn_fdot2(mh3, u2h2(q1.w), a1, false);
        a2 = __builtin_amdgcn_fdot2(mh0, u2h2(q2.x), a2, false);
        a2 = __builtin_amdgcn_fdot2(mh1, u2h2(q2.y), a2, false);
        a2 = __builtin_amdgcn_fdot2(mh2, u2h2(q2.z), a2, false);
        a2 = __builtin_amdgcn_fdot2(mh3, u2h2(q2.w), a2, false);
        a3 = __builtin_amdgcn_fdot2(mh0, u2h2(q3.x), a3, false);
        a3 = __builtin_amdgcn_fdot2(mh1, u2h2(q3.y), a3, false);
        a3 = __builtin_amdgcn_fdot2(mh2, u2h2(q3.z), a3, false);
        a3 = __builtin_amdgcn_fdot2(mh3, u2h2(q3.w), a3, false);
        // folded butterfly within 16-lane j-group
        float t0 = __shfl_xor(f3 ? a0 : a2, 8, 64);
        float t1 = __shfl_xor(f3 ? a1 : a3, 8, 64);
        float c0 = (f3 ? a2 : a0) + t0;
        float c1 = (f3 ? a3 : a1) + t1;
        float t2 = __shfl_xor(fl2 ? c0 : c1, 4, 64);
        float dd = (fl2 ? c1 : c0) + t2;
        dd += __shfl_xor(dd, 2, 64);
        dd += __shfl_xor(dd, 1, 64);
        float x = __expf(dd * TINV);
        z += x;
        if ((lane & 3) == 0)   // lane>>2 = 4j+i; stores contiguous 32B @ item cc
            expS[(size_t)cc * 16 + (lane >> 2)] = f2h(x);
    };

    int c = base;
    for (; c + 1 < end; c += 2) {
        // --- item c (v0, qA) ---
        const int n0 = (int)(v0 >> 20);
        if (n0 != cur_n) {
            if (n0 != pend_n) ldrow(n0);   // prefetch miss: load now
            cvt();
            cur_n = n0;
        }
        const int n1 = (int)(v1 >> 20);
        if (n1 != cur_n && n1 != pend_n) ldrow(n1);   // 1-run-ahead prefetch
        proc(c, qA0, qA1, qA2, qA3);
        {   // refill qA for item c+2
            const uint4* p = e4 + ((size_t)(((unsigned)v2 & 0xFFFFFu) >> 13) * 16 + l4) * 4;
            qA0 = p[0]; qA1 = p[1]; qA2 = p[2]; qA3 = p[3];
        }
        // --- item c+1 (v1, qB) ---
        if (n1 != cur_n) { cvt(); cur_n = n1; }       // pend_n == n1 guaranteed
        const int n2 = (int)(v2 >> 20);
        if (n2 != cur_n && n2 != pend_n) ldrow(n2);
        proc(c + 1, qB0, qB1, qB2, qB3);
        {   // refill qB for item c+3
            const uint4* p = e4 + ((size_t)(((unsigned)v3 & 0xFFFFFu) >> 13) * 16 + l4) * 4;
            qB0 = p[0]; qB1 = p[1]; qB2 = p[2]; qB3 = p[3];
        }
        v0 = v2; v1 = v3;
        v2 = (c + 4 < end) ? inv64[c + 4] : v3;
        v3 = (c + 5 < end) ? inv64[c + 5] : v2;
    }
    if (c < end) {   // tail (odd strip length 65)
        const int n0 = (int)(v0 >> 20);
        if (n0 != cur_n) {
            if (n0 != pend_n) ldrow(n0);
            cvt();
            cur_n = n0;
        }
        proc(c, qA0, qA1, qA2, qA3);
    }

    // cross-wave LDS reduce -> one coalesced 16-lane atomic per block
    __shared__ float s_z[4][16];   // [wave][i*4+j]
    const int i = ((l4 >> 3) << 1) | ((l4 >> 2) & 1);
    if ((lane & 3) == 0) s_z[wv][i * 4 + jj] = z;
    __syncthreads();
    if (tid < 16) {
        float vv = s_z[0][tid] + s_z[1][tid] + s_z[2][tid] + s_z[3][tid];
        const int slot = blockIdx.x & (NSLOT - 1);
        atomicAdd(&Zsl[slot * 16 + tid], vv);
    }
}

// ---------------------------------------------------------------------------
// k_pass2s: pure stream over expS in ref order (no (b,k) decode), all items
// with the NEG formula; per-block masked partial -> one atomicAdd(out).
// Block 0 additionally corrects the 128 positives via posc (pos - neg terms).
// zinv computed from Zsl in-block (replaces k_zred).  grid 1024, block 256.
// ---------------------------------------------------------------------------
__global__ __launch_bounds__(256)
void k_pass2s(const uint4* __restrict__ esu, const float* __restrict__ Zsl,
              const int* __restrict__ posc, float* __restrict__ out) {
    const int tid = threadIdx.x;
    __shared__ float s_zinv[16];   // indexed by half h = 4j+i
    if (tid < 16) {
        const int comp = ((tid & 3) << 2) | (tid >> 2);   // i*4+j
        float s = 0.f;
        for (int sl = 0; sl < NSLOT; ++sl) s += Zsl[sl * 16 + comp];
        float Z = s * (float)((double)NDATA / ((double)BN * (double)KP1));
        s_zinv[tid] = 1.0f / Z;
    }
    __syncthreads();

    float acc[16];
#pragma unroll
    for (int t = 0; t < 16; ++t) acc[t] = 0.f;

    const int NT = gridDim.x * 256;
    for (int t = blockIdx.x * 256 + tid; t < TREFS; t += NT) {
        uint4 p0 = esu[(size_t)t * 2];
        uint4 p1 = esu[(size_t)t * 2 + 1];
        unsigned int wds[8] = {p0.x, p0.y, p0.z, p0.w, p1.x, p1.y, p1.z, p1.w};
#pragma unroll
        for (int w = 0; w < 8; ++w) {
            float v0 = h_lo(wds[w]) * s_zinv[2*w];
            float v1 = h_hi(wds[w]) * s_zinv[2*w+1];
            acc[2*w]   += -__logf(1.f + (v0 + EPS_C) * (1.f / MPN));
            acc[2*w+1] += -__logf(1.f + (v1 + EPS_C) * (1.f / MPN));
        }
    }

#pragma unroll
    for (int t = 0; t < 16; ++t) {
#pragma unroll
        for (int off = 32; off > 0; off >>= 1)
            acc[t] += __shfl_down(acc[t], off, 64);
    }
    __shared__ float s_a[4][16];
    const int wv = tid >> 6;
    if ((tid & 63) == 0) {
#pragma unroll
        for (int t = 0; t < 16; ++t) s_a[wv][t] = acc[t];
    }
    __syncthreads();
    if (tid < 16) {
        float v = s_a[0][tid] + s_a[1][tid] + s_a[2][tid] + s_a[3][tid];
        v = ((tid >> 2) != (tid & 3)) ? v : 0.f;   // mask i != j (h = 4j+i)
        v += __shfl_down(v, 8, 64);
        v += __shfl_down(v, 4, 64);
        v += __shfl_down(v, 2, 64);
        v += __shfl_down(v, 1, 64);
        if (tid == 0) atomicAdd(out, -v / (float)BN);
    }

    // correction for the 128 positive (k==0) items
    if (blockIdx.x == 0) {
        float corr = 0.f;
        if (tid < BN) {
            const int cc = posc[tid];
            uint4 p0 = esu[(size_t)cc * 2];
            uint4 p1 = esu[(size_t)cc * 2 + 1];
            unsigned int wds[8] = {p0.x, p0.y, p0.z, p0.w, p1.x, p1.y, p1.z, p1.w};
#pragma unroll
            for (int w = 0; w < 8; ++w) {
#pragma unroll
                for (int hl = 0; hl < 2; ++hl) {
                    const int h = 2 * w + hl;
                    if ((h >> 2) != (h & 3)) {
                        float val = hl ? h_hi(wds[w]) : h_lo(wds[w]);
                        float v = val * s_zinv[h];
                        float posT = -__logf(1.f + (MPN + EPS_C) / v);
                        float negT = -__logf(1.f + (v + EPS_C) * (1.f / MPN));
                        corr += posT - negT;
                    }
                }
            }
        }
        for (int off = 32; off > 0; off >>= 1)
            corr += __shfl_down(corr, off, 64);
        __shared__ float s_c[4];
        if ((tid & 63) == 0) s_c[wv] = corr;
        __syncthreads();
        if (tid == 0)
            atomicAdd(out, -(s_c[0] + s_c[1] + s_c[2] + s_c[3]) / (float)BN);
    }
}

// ---------------------------------------------------------------------------
// fp32 fallback pieces (only if workspace too small for the full path)
// ---------------------------------------------------------------------------
__global__ void k_feat(const float* __restrict__ e0, const float* __restrict__ e1,
                       const float* __restrict__ e2, const float* __restrict__ e3,
                       const float* __restrict__ W, const float* __restrict__ bias,
                       float* __restrict__ e_out) {
    const int r = blockIdx.x;
    const int b = blockIdx.y;
    const float* emb = (r == 0 ? e0 : r == 1 ? e1 : r == 2 ? e2 : e3) + (size_t)b * REP;

    __shared__ float s_emb[REP];
    for (int i = threadIdx.x; i < REP; i += blockDim.x) s_emb[i] = emb[i];
    __syncthreads();

    const int d = threadIdx.x;
    const float4* wrow = (const float4*)(W + ((size_t)r * FD + d) * REP);
    float acc = 0.f;
#pragma unroll 8
    for (int c = 0; c < REP / 4; ++c) {
        float4 v = wrow[c];
        acc += v.x * s_emb[4*c+0] + v.y * s_emb[4*c+1]
             + v.z * s_emb[4*c+2] + v.w * s_emb[4*c+3];
    }
    float h = acc + bias[r * FD + d];

    __shared__ float red[FD];
    red[d] = h * h;
    __syncthreads();
    for (int off = FD / 2; off > 0; off >>= 1) {
        if (d < off) red[d] += red[d + off];
        __syncthreads();
    }
    float nrm = sqrtf(red[0]);
    e_out[((size_t)r * BN + b) * FD + d] = h / nrm;
}

static __device__ __forceinline__ void dot4(const float4* __restrict__ row,
                                            const float* __restrict__ se,
                                            float& a0, float& a1, float& a2, float& a3) {
    a0 = a1 = a2 = a3 = 0.f;
#pragma unroll 8
    for (int c = 0; c < FD / 4; ++c) {
        float4 v = row[c];
        const int o = 4 * c;
        a0 += v.x * se[0*FD+o+0] + v.y * se[0*FD+o+1] + v.z * se[0*FD+o+2] + v.w * se[0*FD+o+3];
        a1 += v.x * se[1*FD+o+0] + v.y * se[1*FD+o+1] + v.z * se[1*FD+o+2] + v.w * se[1*FD+o+3];
        a2 += v.x * se[2*FD+o+0] + v.y * se[2*FD+o+1] + v.z * se[2*FD+o+2] + v.w * se[2*FD+o+3];
        a3 += v.x * se[3*FD+o+0] + v.y * se[3*FD+o+1] + v.z * se[3*FD+o+2] + v.w * se[3*FD+o+3];
    }
}

static __device__ __forceinline__ void block_reduce4(float z0, float z1, float z2,
                                                     float z3, float* dst, int j) {
    __shared__ float sred[256];
    float zs[NBR] = {z0, z1, z2, z3};
    for (int i = 0; i < NBR; ++i) {
        sred[threadIdx.x] = zs[i];
        __syncthreads();
        for (int off = 128; off > 0; off >>= 1) {
            if ((int)threadIdx.x < off) sred[threadIdx.x] += sred[threadIdx.x + off];
            __syncthreads();
        }
        if (threadIdx.x == 0) atomicAdd(&dst[i * NBR + j], sred[0]);
        __syncthreads();
    }
}

static __device__ __forceinline__ float term_of(float ex, float zinv, int k) {
    const float c = MPN + EPS_C;
    float v = ex * zinv;
    if (k == 0) return -__logf(1.0f + c / v);
    return -__logf(1.0f + (v + EPS_C) * (1.0f / MPN));
}

template <bool STORE>
__global__ void k_pass1_f32(const float* __restrict__ e, const float* __restrict__ memory,
                            const int* __restrict__ cidx,
                            float* __restrict__ Zsum, ushort4* __restrict__ expS) {
    const int j = blockIdx.z;
    const int b = blockIdx.y;

    __shared__ float s_e[NBR * FD];
    for (int t = threadIdx.x; t < NBR * FD; t += blockDim.x) {
        int i = t >> 7, d = t & (FD - 1);
        s_e[t] = e[((size_t)i * BN + b) * FD + d];
    }
    __syncthreads();

    const int* ci = cidx + (size_t)b * KP1;
    const float4* mem4 = (const float4*)(memory + (size_t)j * NDATA * FD);
    float z0 = 0.f, z1 = 0.f, z2 = 0.f, z3 = 0.f;

    for (int k = threadIdx.x + blockIdx.x * blockDim.x; k < KP1;
         k += blockDim.x * gridDim.x) {
        const int n = ci[k];
        const float4* row = mem4 + (size_t)n * (FD / 4);
        float a0, a1, a2, a3;
        dot4(row, s_e, a0, a1, a2, a3);
        float x0 = __expf(a0 * TINV);
        float x1 = __expf(a1 * TINV);
        float x2 = __expf(a2 * TINV);
        float x3 = __expf(a3 * TINV);
        z0 += x0; z1 += x1; z2 += x2; z3 += x3;
        if (STORE) {
            ushort4 st;
            st.x = f2bf(x0); st.y = f2bf(x1); st.z = f2bf(x2); st.w = f2bf(x3);
            expS[((size_t)j * BN + b) * KP1 + k] = st;
        }
    }
    block_reduce4(z0, z1, z2, z3, Zsum, j);
}

__global__ void k_pass2_stored(const ushort4* __restrict__ expS,
                               const float* __restrict__ Zsum,
                               float* __restrict__ accum) {
    const int j = blockIdx.z;
    const int b = blockIdx.y;

    __shared__ float s_zinv[NBR];
    if (threadIdx.x < NBR) {
        float Z = Zsum[threadIdx.x * NBR + j] *
                  (float)((double)NDATA / ((double)BN * (double)KP1));
        s_zinv[threadIdx.x] = 1.0f / Z;
    }
    __syncthreads();

    const ushort4* es = expS + ((size_t)j * BN + b) * KP1;
    float a0 = 0.f, a1 = 0.f, a2 = 0.f, a3 = 0.f;

    for (int k = threadIdx.x + blockIdx.x * blockDim.x; k < KP1;
         k += blockDim.x * gridDim.x) {
        ushort4 v = es[k];
        a0 += term_of(bf2f(v.x), s_zinv[0], k);
        a1 += term_of(bf2f(v.y), s_zinv[1], k);
        a2 += term_of(bf2f(v.z), s_zinv[2], k);
        a3 += term_of(bf2f(v.w), s_zinv[3], k);
    }
    block_reduce4(a0, a1, a2, a3, accum, j);
}

__global__ void k_pass2_regather(const float* __restrict__ e, const float* __restrict__ memory,
                                 const int* __restrict__ cidx,
                                 const float* __restrict__ Zsum, float* __restrict__ accum) {
    const int j = blockIdx.z;
    const int b = blockIdx.y;

    __shared__ float s_e[NBR * FD];
    __shared__ float s_zinv[NBR];
    for (int t = threadIdx.x; t < NBR * FD; t += blockDim.x) {
        int i = t >> 7, d = t & (FD - 1);
        s_e[t] = e[((size_t)i * BN + b) * FD + d];
    }
    if (threadIdx.x < NBR) {
        float Z = Zsum[threadIdx.x * NBR + j] *
                  (float)((double)NDATA / ((double)BN * (double)KP1));
        s_zinv[threadIdx.x] = 1.0f / Z;
    }
    __syncthreads();

    const int* ci = cidx + (size_t)b * KP1;
    const float4* mem4 = (const float4*)(memory + (size_t)j * NDATA * FD);
    float a0s = 0.f, a1s = 0.f, a2s = 0.f, a3s = 0.f;

    for (int k = threadIdx.x + blockIdx.x * blockDim.x; k < KP1;
         k += blockDim.x * gridDim.x) {
        const int n = ci[k];
        const float4* row = mem4 + (size_t)n * (FD / 4);
        float a0, a1, a2, a3;
        dot4(row, s_e, a0, a1, a2, a3);
        a0s += term_of(__expf(a0 * TINV), s_zinv[0], k);
        a1s += term_of(__expf(a1 * TINV), s_zinv[1], k);
        a2s += term_of(__expf(a2 * TINV), s_zinv[2], k);
        a3s += term_of(__expf(a3 * TINV), s_zinv[3], k);
    }
    block_reduce4(a0s, a1s, a2s, a3s, accum, j);
}

__global__ void k_init(float* __restrict__ p, int n) {
    int i = blockIdx.x * blockDim.x + threadIdx.x;
    if (i < n) p[i] = 0.f;
}

__global__ void k_final_legacy(const float* __restrict__ accum, float* __restrict__ out) {
    if (threadIdx.x == 0) {
        float s = 0.f;
        for (int i = 0; i < NBR; ++i)
            for (int j = 0; j < NBR; ++j)
                if (i != j) s += -accum[i * NBR + j] / (float)BN;
        out[0] = s;
    }
}

// ---------------------------------------------------------------------------
extern "C" void kernel_launch(void* const* d_in, const int* in_sizes, int n_in,
                              void* d_out, int out_size, void* d_ws, size_t ws_size,
                              hipStream_t stream) {
    const float* e0   = (const float*)d_in[0];
    const float* e1   = (const float*)d_in[1];
    const float* e2   = (const float*)d_in[2];
    const float* e3   = (const float*)d_in[3];
    const float* W    = (const float*)d_in[4];
    const float* bias = (const float*)d_in[5];
    const float* mem  = (const float*)d_in[6];
    const int*   cidx = (const int*)d_in[8];
    float* out = (float*)d_out;

    // ws (floats): e[65536] | Zsum[16] | accum[16] | Zsl[1024] | Asl[1024]
    // then (bytes, 16-aligned): counts | fill | cursor | start | inv64 | expS | eh2 | posc
    float* ws    = (float*)d_ws;
    float* e     = ws;
    float* Zsum  = ws + 65536;
    float* accum = ws + 65552;
    float* Zsl   = ws + 65568;
    const size_t base_b  = (size_t)67616 * 4;               // 270,464 B
    const size_t cnt_b   = (size_t)NDATA * 4;               // 400,000 B
    const size_t inv_b   = (size_t)TREFS * 8;               // 4,195,328 B
    const size_t expS_b  = (size_t)TREFS * 16 * 2;          // 16,781,312 B
    const size_t eh2_b   = (size_t)BN * 16 * 4 * 8 * 2;     // 131,072 B

    const size_t off_counts = base_b;
    const size_t off_fill   = off_counts + cnt_b;
    const size_t off_cursor = off_fill + cnt_b;
    const size_t off_start  = off_cursor + 16;
    const size_t off_inv    = off_start + cnt_b;
    const size_t off_expS   = off_inv + inv_b;
    const size_t off_eh2    = off_expS + expS_b;
    const size_t off_posc   = off_eh2 + eh2_b;

    const size_t need_main = off_posc + 512;                // ~22.7 MB
    const size_t need_mid  = base_b + expS_b;               // ~17.05 MB

    if (ws_size >= need_main) {
        int* counts  = (int*)((char*)d_ws + off_counts);
        int* fill    = (int*)((char*)d_ws + off_fill);
        int* cursor  = (int*)((char*)d_ws + off_cursor);
        int* start   = (int*)((char*)d_ws + off_start);
        unsigned long long* inv64 = (unsigned long long*)((char*)d_ws + off_inv);
        ushort* expS = (ushort*)((char*)d_ws + off_expS);
        ushort* eh2  = (ushort*)((char*)d_ws + off_eh2);
        int* posc    = (int*)((char*)d_ws + off_posc);

        k_init2<<<782, 256, 0, stream>>>(counts, Zsl, out);
        k_fh<<<NBR * BN + 256, 256, 0, stream>>>(e0, e1, e2, e3, W, bias, cidx,
                                                 eh2, counts);
        k_assign<<<391, 256, 0, stream>>>(counts, start, cursor);
        k_scatter<<<dim3(17, BN), 256, 0, stream>>>(cidx, start, fill, inv64, posc);
        k_pass1i<<<2048, 256, 0, stream>>>(mem, eh2, inv64, Zsl, expS);
        k_pass2s<<<1024, 256, 0, stream>>>((const uint4*)expS, Zsl, posc, out);
    } else {
        k_init<<<9, 256, 0, stream>>>(Zsum, 2080);
        k_feat<<<dim3(NBR, BN), 128, 0, stream>>>(e0, e1, e2, e3, W, bias, e);
        if (ws_size >= need_mid) {
            ushort4* expS = (ushort4*)((char*)d_ws + base_b);
            k_pass1_f32<true><<<dim3(4, BN, NBR), 256, 0, stream>>>(e, mem, cidx, Zsum, expS);
            k_pass2_stored<<<dim3(4, BN, NBR), 256, 0, stream>>>(expS, Zsum, accum);
        } else {
            k_pass1_f32<false><<<dim3(4, BN, NBR), 256, 0, stream>>>(e, mem, cidx, Zsum, nullptr);
            k_pass2_regather<<<dim3(4, BN, NBR), 256, 0, stream>>>(e, mem, cidx, Zsum, accum);
        }
        k_final_legacy<<<1, 64, 0, stream>>>(accum, out);
    }
}

// Round 5
// 471.231 us; speedup vs baseline: 1.7746x; 1.1150x over previous
//
#include <hip/hip_runtime.h>
#include <math.h>

#define NBR    4        // NUM_BRANCHES
#define REP    1024     // REP_DIM
#define FD     128      // FEAT_DIM
#define NDATA  100000
#define KP1    4097     // NCE_K + 1
#define BN     128      // BATCH
#define MPN    0.04096f // m * Pn = 4096 / 100000
#define EPS_C  1e-7f
#define TINV   (1.0f / 0.07f)
#define NSLOT  64       // atomic slots for Z partial sums
#define TREFS  (BN * KP1)   // 524,416 total (b,k) refs

typedef _Float16 half2e  __attribute__((ext_vector_type(2)));
typedef float    floatx4 __attribute__((ext_vector_type(4)));

// ---------------------------------------------------------------------------
// fp16 helpers
// ---------------------------------------------------------------------------
static __device__ __forceinline__ unsigned short f2h(float f) {
    union { _Float16 h; unsigned short u; } c; c.h = (_Float16)f; return c.u;
}
static __device__ __forceinline__ float h_lo(unsigned int u) {
    union { unsigned int u; _Float16 h[2]; } c; c.u = u; return (float)c.h[0];
}
static __device__ __forceinline__ float h_hi(unsigned int u) {
    union { unsigned int u; _Float16 h[2]; } c; c.u = u; return (float)c.h[1];
}
static __device__ __forceinline__ half2e u2h2(unsigned int u) {
    union { unsigned int u; half2e h; } c; c.u = u; return c.h;
}
static __device__ __forceinline__ unsigned short f2bf(float f) {
    union { float f; unsigned int u; } c; c.f = f;
    unsigned int u = c.u;
    u += 0x7fffu + ((u >> 16) & 1u);
    return (unsigned short)(u >> 16);
}
static __device__ __forceinline__ float bf2f(unsigned short h) {
    union { unsigned int u; float f; } c; c.u = ((unsigned int)h) << 16;
    return c.f;
}

// ---------------------------------------------------------------------------
// k_init2: zero counts+fill+cursor (contiguous 200004 ints), Zsl, out.
// ---------------------------------------------------------------------------
__global__ void k_init2(int* __restrict__ cnts, float* __restrict__ Zsl,
                        float* __restrict__ out) {
    const int i = blockIdx.x * 256 + threadIdx.x;
    if (i < 200004) cnts[i] = 0;
    if (i < NSLOT * 16) Zsl[i] = 0.f;
    if (i == 0) out[0] = 0.f;
}

// ---------------------------------------------------------------------------
// k_fh: blocks [0,512): feat -> packed f16 e: eh2[b][d>>3][i][d&7].
// blocks [512,768): hist counts[n].   (validated r3/r4)
// ---------------------------------------------------------------------------
__global__ __launch_bounds__(256)
void k_fh(const float* __restrict__ e0, const float* __restrict__ e1,
          const float* __restrict__ e2, const float* __restrict__ e3,
          const float* __restrict__ W, const float* __restrict__ bias,
          const int* __restrict__ cidx,
          ushort* __restrict__ eh2, int* __restrict__ counts) {
    const int tid = threadIdx.x;
    if ((int)blockIdx.x < NBR * BN) {
        __shared__ float s_emb[REP];
        __shared__ float s_part[256];
        __shared__ float s_sq[FD];
        const int u = blockIdx.x;
        const int r = u >> 7;
        const int b = u & 127;
        const float* emb = (r == 0 ? e0 : r == 1 ? e1 : r == 2 ? e2 : e3)
                           + (size_t)b * REP;
        for (int t = tid; t < REP; t += 256) s_emb[t] = emb[t];
        __syncthreads();
        const int d  = tid & 127;
        const int kh = tid >> 7;
        const float4* wrow = (const float4*)(W + ((size_t)r * FD + d) * REP)
                             + kh * 128;
        const float* se = s_emb + (kh << 9);
        float a = 0.f;
#pragma unroll 4
        for (int c = 0; c < 128; ++c) {
            float4 v = wrow[c];
            a += v.x * se[4*c+0] + v.y * se[4*c+1]
               + v.z * se[4*c+2] + v.w * se[4*c+3];
        }
        s_part[tid] = a;
        __syncthreads();
        float h = 0.f;
        if (kh == 0) {
            h = s_part[d] + s_part[128 + d] + bias[r * FD + d];
            s_sq[d] = h * h;
        }
        __syncthreads();
        for (int off = 64; off > 0; off >>= 1) {
            if (tid < off) s_sq[tid] += s_sq[tid + off];
            __syncthreads();
        }
        float nrm = sqrtf(s_sq[0]);
        if (kh == 0) {
            eh2[((size_t)(b * 16 + (d >> 3)) * 4 + r) * 8 + (d & 7)]
                = f2h(h / nrm);
        }
    } else {
        const int NT = 256 * 256;
        for (int t = ((int)blockIdx.x - NBR * BN) * 256 + tid; t < TREFS; t += NT)
            atomicAdd(&counts[cidx[t]], 1);
    }
}

// ---------------------------------------------------------------------------
// k_assign: start[n] = running offset of bucket n (block scan + atomic cursor).
// ---------------------------------------------------------------------------
__global__ void k_assign(const int* __restrict__ counts, int* __restrict__ start,
                         int* __restrict__ cursor) {
    __shared__ int s[256];
    __shared__ int sbase;
    const int tid = threadIdx.x;
    const int n = blockIdx.x * 256 + tid;
    int c = (n < NDATA) ? counts[n] : 0;
    s[tid] = c;
    __syncthreads();
#pragma unroll
    for (int off = 1; off < 256; off <<= 1) {
        int v = (tid >= off) ? s[tid - off] : 0;
        __syncthreads();
        s[tid] += v;
        __syncthreads();
    }
    if (tid == 255) sbase = atomicAdd(cursor, s[255]);
    __syncthreads();
    if (n < NDATA) start[n] = sbase + s[tid] - c;
}

// ---------------------------------------------------------------------------
// k_scatter: inv64[start[n]+pos] = (n<<20)|(b<<13)|k; posc[b] = c of k==0.
// ---------------------------------------------------------------------------
__global__ void k_scatter(const int* __restrict__ cidx, const int* __restrict__ start,
                          int* __restrict__ fill, unsigned long long* __restrict__ inv64,
                          int* __restrict__ posc) {
    const int k = blockIdx.x * 256 + threadIdx.x;
    if (k >= KP1) return;
    const int b = blockIdx.y;
    const int n = cidx[(size_t)b * KP1 + k];
    const int pos = atomicAdd(&fill[n], 1);
    const int c = start[n] + pos;
    inv64[c] =
        ((unsigned long long)(unsigned int)n << 20) |
        ((unsigned long long)(unsigned int)b << 13) |
        (unsigned long long)(unsigned int)k;
    if (k == 0) posc[b] = c;
}

// ---------------------------------------------------------------------------
// k_pass1L: LDS-resident e-table version.
//  - 256 blocks x 1024 threads (16 waves); 1 block/CU (128 KB dynamic LDS).
//  - e-table (128 KB) loaded once per block with bank-swizzle: chunk (b,l4,q)
//    at slot s=(q+((l4>>1)&3))&3 -> every wave ds_read_b128 is 2-way (free).
//  - inner loop = round-2 simple body: row-load-on-change + vnext lookahead.
//  - expS stored at ref-order index c (sequential 32B per wave).
// ---------------------------------------------------------------------------
__global__ __launch_bounds__(1024)
void k_pass1L(const float* __restrict__ mem, const ushort* __restrict__ eh2g,
              const unsigned long long* __restrict__ inv64,
              float* __restrict__ Zsl, ushort* __restrict__ expS) {
    extern __shared__ char smem[];           // 131072 B e-table
    const int tid  = threadIdx.x;
    const int lane = tid & 63;
    const int wv   = tid >> 6;               // 0..15
    const int l4   = lane & 15;
    const int jj   = lane >> 4;
    const bool f3  = (l4 & 8) != 0;
    const bool fl2 = (l4 & 4) != 0;

    // ---- fill LDS e-table with swizzle ----
    {
        const uint4* src = (const uint4*)eh2g;
        uint4* dst = (uint4*)smem;
        for (int ch = tid; ch < 8192; ch += 1024) {
            const int q   = ch & 3;
            const int cl4 = (ch >> 2) & 15;
            const int cb  = ch >> 6;
            const int s   = (q + ((cl4 >> 1) & 3)) & 3;
            dst[cb * 64 + cl4 * 4 + s] = src[ch];
        }
    }
    __syncthreads();

    // per-lane swizzled byte offsets for q=0..3
    const int l4h = (l4 >> 1) & 3;
    const int o0 = (l4 * 4 + ((0 + l4h) & 3)) * 16;
    const int o1 = (l4 * 4 + ((1 + l4h) & 3)) * 16;
    const int o2 = (l4 * 4 + ((2 + l4h) & 3)) * 16;
    const int o3 = (l4 * 4 + ((3 + l4h) & 3)) * 16;

    // ---- strip assignment: 4096 waves x 128 items (first 128 get 129) ----
    const int g    = (int)blockIdx.x * 16 + wv;
    const int base = g * 128 + (g < 128 ? g : 128);
    const int end  = base + 128 + (g < 128 ? 1 : 0);

    const float* mrow = mem + (size_t)jj * (NDATA * FD) + l4 * 8;
    ushort* esp = expS + (size_t)base * 16 + (lane >> 2);

    float z = 0.f;
    int n_prev = -1;
    half2e mh0 = half2e{(_Float16)0.f, (_Float16)0.f};
    half2e mh1 = mh0, mh2 = mh0, mh3 = mh0;

    unsigned long long vnext = inv64[base];
    for (int c = base; c < end; ++c, esp += 16) {
        const unsigned long long v = vnext;
        if (c + 1 < end) vnext = inv64[c + 1];
        const int n = (int)(v >> 20);
        const int b = (int)(((unsigned)v >> 13) & 127u);

        // e-fragments from LDS (2-way conflict = free; lanes 16j+l4 broadcast)
        const char* eb = smem + (b << 10);
        uint4 ev0 = *(const uint4*)(eb + o0);
        uint4 ev1 = *(const uint4*)(eb + o1);
        uint4 ev2 = *(const uint4*)(eb + o2);
        uint4 ev3 = *(const uint4*)(eb + o3);

        if (n != n_prev) {   // wave-uniform, avg run length 5.24
            const floatx4* mp = (const floatx4*)(mrow + (size_t)n * FD);
            floatx4 r0 = __builtin_nontemporal_load(mp);
            floatx4 r1 = __builtin_nontemporal_load(mp + 1);
            mh0 = half2e{(_Float16)r0.x, (_Float16)r0.y};
            mh1 = half2e{(_Float16)r0.z, (_Float16)r0.w};
            mh2 = half2e{(_Float16)r1.x, (_Float16)r1.y};
            mh3 = half2e{(_Float16)r1.z, (_Float16)r1.w};
            n_prev = n;
        }

        float a0 = 0.f, a1 = 0.f, a2 = 0.f, a3 = 0.f;
        a0 = __builtin_amdgcn_fdot2(mh0, u2h2(ev0.x), a0, false);
        a0 = __builtin_amdgcn_fdot2(mh1, u2h2(ev0.y), a0, false);
        a0 = __builtin_amdgcn_fdot2(mh2, u2h2(ev0.z), a0, false);
        a0 = __builtin_amdgcn_fdot2(mh3, u2h2(ev0.w), a0, false);
        a1 = __builtin_amdgcn_fdot2(mh0, u2h2(ev1.x), a1, false);
        a1 = __builtin_amdgcn_fdot2(mh1, u2h2(ev1.y), a1, false);
        a1 = __builtin_amdgcn_fdot2(mh2, u2h2(ev1.z), a1, false);
        a1 = __builtin_amdgcn_fdot2(mh3, u2h2(ev1.w), a1, false);
        a2 = __builtin_amdgcn_fdot2(mh0, u2h2(ev2.x), a2, false);
        a2 = __builtin_amdgcn_fdot2(mh1, u2h2(ev2.y), a2, false);
        a2 = __builtin_amdgcn_fdot2(mh2, u2h2(ev2.z), a2, false);
        a2 = __builtin_amdgcn_fdot2(mh3, u2h2(ev2.w), a2, false);
        a3 = __builtin_amdgcn_fdot2(mh0, u2h2(ev3.x), a3, false);
        a3 = __builtin_amdgcn_fdot2(mh1, u2h2(ev3.y), a3, false);
        a3 = __builtin_amdgcn_fdot2(mh2, u2h2(ev3.z), a3, false);
        a3 = __builtin_amdgcn_fdot2(mh3, u2h2(ev3.w), a3, false);

        // folded butterfly within 16-lane j-group (validated r2)
        float t0 = __shfl_xor(f3 ? a0 : a2, 8, 64);
        float t1 = __shfl_xor(f3 ? a1 : a3, 8, 64);
        float c0 = (f3 ? a2 : a0) + t0;
        float c1 = (f3 ? a3 : a1) + t1;
        float t2 = __shfl_xor(fl2 ? c0 : c1, 4, 64);
        float dd = (fl2 ? c1 : c0) + t2;
        dd += __shfl_xor(dd, 2, 64);
        dd += __shfl_xor(dd, 1, 64);
        float x = __expf(dd * TINV);
        z += x;
        if ((lane & 3) == 0) *esp = f2h(x);
    }

    // cross-wave reduce -> one coalesced 16-lane atomic per block
    __shared__ float s_z[16][16];   // [wave][i*4+j]
    const int i = ((l4 >> 3) << 1) | ((l4 >> 2) & 1);
    if ((lane & 3) == 0) s_z[wv][i * 4 + jj] = z;
    __syncthreads();
    if (tid < 16) {
        float vv = 0.f;
#pragma unroll
        for (int w = 0; w < 16; ++w) vv += s_z[w][tid];
        const int slot = blockIdx.x & (NSLOT - 1);
        atomicAdd(&Zsl[slot * 16 + tid], vv);
    }
}

// ---------------------------------------------------------------------------
// k_pass1i: global-e fallback (round-4 version, known-correct; used only if
// the 128 KB dynamic-LDS launch is rejected).
// ---------------------------------------------------------------------------
__global__ __launch_bounds__(256)
void k_pass1i(const float* __restrict__ mem, const ushort* __restrict__ eh2,
              const unsigned long long* __restrict__ inv64,
              float* __restrict__ Zsl, ushort* __restrict__ expS) {
    const int tid  = threadIdx.x;
    const int lane = tid & 63;
    const int wv   = tid >> 6;
    const int g    = ((int)blockIdx.x << 2) + wv;
    const int l4   = lane & 15;
    const int jj   = lane >> 4;
    const bool f3  = (l4 & 8) != 0;
    const bool fl2 = (l4 & 4) != 0;

    const int base = g * 64 + (g < 128 ? g : 128);
    const int end  = base + 64 + (g < 128 ? 1 : 0);

    const float* mrow = mem + (size_t)jj * (NDATA * FD) + l4 * 8;
    const uint4* e4   = (const uint4*)eh2;

    float z = 0.f;
    int n_prev = -1;
    half2e mh0 = half2e{(_Float16)0.f, (_Float16)0.f};
    half2e mh1 = mh0, mh2 = mh0, mh3 = mh0;

    unsigned long long vnext = inv64[base];
    for (int c = base; c < end; ++c) {
        const unsigned long long v = vnext;
        if (c + 1 < end) vnext = inv64[c + 1];
        const int n = (int)(v >> 20);
        const int b = (int)(((unsigned)v >> 13) & 127u);

        const uint4* p = e4 + ((size_t)b * 16 + l4) * 4;
        uint4 ev0 = p[0], ev1 = p[1], ev2 = p[2], ev3 = p[3];

        if (n != n_prev) {
            const floatx4* mp = (const floatx4*)(mrow + (size_t)n * FD);
            floatx4 r0 = __builtin_nontemporal_load(mp);
            floatx4 r1 = __builtin_nontemporal_load(mp + 1);
            mh0 = half2e{(_Float16)r0.x, (_Float16)r0.y};
            mh1 = half2e{(_Float16)r0.z, (_Float16)r0.w};
            mh2 = half2e{(_Float16)r1.x, (_Float16)r1.y};
            mh3 = half2e{(_Float16)r1.z, (_Float16)r1.w};
            n_prev = n;
        }

        float a0 = 0.f, a1 = 0.f, a2 = 0.f, a3 = 0.f;
        a0 = __builtin_amdgcn_fdot2(mh0, u2h2(ev0.x), a0, false);
        a0 = __builtin_amdgcn_fdot2(mh1, u2h2(ev0.y), a0, false);
        a0 = __builtin_amdgcn_fdot2(mh2, u2h2(ev0.z), a0, false);
        a0 = __builtin_amdgcn_fdot2(mh3, u2h2(ev0.w), a0, false);
        a1 = __builtin_amdgcn_fdot2(mh0, u2h2(ev1.x), a1, false);
        a1 = __builtin_amdgcn_fdot2(mh1, u2h2(ev1.y), a1, false);
        a1 = __builtin_amdgcn_fdot2(mh2, u2h2(ev1.z), a1, false);
        a1 = __builtin_amdgcn_fdot2(mh3, u2h2(ev1.w), a1, false);
        a2 = __builtin_amdgcn_fdot2(mh0, u2h2(ev2.x), a2, false);
        a2 = __builtin_amdgcn_fdot2(mh1, u2h2(ev2.y), a2, false);
        a2 = __builtin_amdgcn_fdot2(mh2, u2h2(ev2.z), a2, false);
        a2 = __builtin_amdgcn_fdot2(mh3, u2h2(ev2.w), a2, false);
        a3 = __builtin_amdgcn_fdot2(mh0, u2h2(ev3.x), a3, false);
        a3 = __builtin_amdgcn_fdot2(mh1, u2h2(ev3.y), a3, false);
        a3 = __builtin_amdgcn_fdot2(mh2, u2h2(ev3.z), a3, false);
        a3 = __builtin_amdgcn_fdot2(mh3, u2h2(ev3.w), a3, false);

        float t0 = __shfl_xor(f3 ? a0 : a2, 8, 64);
        float t1 = __shfl_xor(f3 ? a1 : a3, 8, 64);
        float c0 = (f3 ? a2 : a0) + t0;
        float c1 = (f3 ? a3 : a1) + t1;
        float t2 = __shfl_xor(fl2 ? c0 : c1, 4, 64);
        float dd = (fl2 ? c1 : c0) + t2;
        dd += __shfl_xor(dd, 2, 64);
        dd += __shfl_xor(dd, 1, 64);
        float x = __expf(dd * TINV);
        z += x;
        if ((lane & 3) == 0)
            expS[(size_t)c * 16 + (lane >> 2)] = f2h(x);
    }

    __shared__ float s_z[4][16];
    const int i = ((l4 >> 3) << 1) | ((l4 >> 2) & 1);
    if ((lane & 3) == 0) s_z[wv][i * 4 + jj] = z;
    __syncthreads();
    if (tid < 16) {
        float vv = s_z[0][tid] + s_z[1][tid] + s_z[2][tid] + s_z[3][tid];
        const int slot = blockIdx.x & (NSLOT - 1);
        atomicAdd(&Zsl[slot * 16 + tid], vv);
    }
}

// ---------------------------------------------------------------------------
// k_pass2s: stream expS in ref order; all-NEG + posc correction (validated r4).
// ---------------------------------------------------------------------------
__global__ __launch_bounds__(256)
void k_pass2s(const uint4* __restrict__ esu, const float* __restrict__ Zsl,
              const int* __restrict__ posc, float* __restrict__ out) {
    const int tid = threadIdx.x;
    __shared__ float s_zinv[16];   // indexed by half h = 4j+i
    if (tid < 16) {
        const int comp = ((tid & 3) << 2) | (tid >> 2);   // i*4+j
        float s = 0.f;
        for (int sl = 0; sl < NSLOT; ++sl) s += Zsl[sl * 16 + comp];
        float Z = s * (float)((double)NDATA / ((double)BN * (double)KP1));
        s_zinv[tid] = 1.0f / Z;
    }
    __syncthreads();

    float acc[16];
#pragma unroll
    for (int t = 0; t < 16; ++t) acc[t] = 0.f;

    const int NT = gridDim.x * 256;
    for (int t = blockIdx.x * 256 + tid; t < TREFS; t += NT) {
        uint4 p0 = esu[(size_t)t * 2];
        uint4 p1 = esu[(size_t)t * 2 + 1];
        unsigned int wds[8] = {p0.x, p0.y, p0.z, p0.w, p1.x, p1.y, p1.z, p1.w};
#pragma unroll
        for (int w = 0; w < 8; ++w) {
            float v0 = h_lo(wds[w]) * s_zinv[2*w];
            float v1 = h_hi(wds[w]) * s_zinv[2*w+1];
            acc[2*w]   += -__logf(1.f + (v0 + EPS_C) * (1.f / MPN));
            acc[2*w+1] += -__logf(1.f + (v1 + EPS_C) * (1.f / MPN));
        }
    }

#pragma unroll
    for (int t = 0; t < 16; ++t) {
#pragma unroll
        for (int off = 32; off > 0; off >>= 1)
            acc[t] += __shfl_down(acc[t], off, 64);
    }
    __shared__ float s_a[4][16];
    const int wv = tid >> 6;
    if ((tid & 63) == 0) {
#pragma unroll
        for (int t = 0; t < 16; ++t) s_a[wv][t] = acc[t];
    }
    __syncthreads();
    if (tid < 16) {
        float v = s_a[0][tid] + s_a[1][tid] + s_a[2][tid] + s_a[3][tid];
        v = ((tid >> 2) != (tid & 3)) ? v : 0.f;   // mask i != j (h = 4j+i)
        v += __shfl_down(v, 8, 64);
        v += __shfl_down(v, 4, 64);
        v += __shfl_down(v, 2, 64);
        v += __shfl_down(v, 1, 64);
        if (tid == 0) atomicAdd(out, -v / (float)BN);
    }

    if (blockIdx.x == 0) {   // correction for the 128 positive (k==0) items
        float corr = 0.f;
        if (tid < BN) {
            const int cc = posc[tid];
            uint4 p0 = esu[(size_t)cc * 2];
            uint4 p1 = esu[(size_t)cc * 2 + 1];
            unsigned int wds[8] = {p0.x, p0.y, p0.z, p0.w, p1.x, p1.y, p1.z, p1.w};
#pragma unroll
            for (int w = 0; w < 8; ++w) {
#pragma unroll
                for (int hl = 0; hl < 2; ++hl) {
                    const int h = 2 * w + hl;
                    if ((h >> 2) != (h & 3)) {
                        float val = hl ? h_hi(wds[w]) : h_lo(wds[w]);
                        float v = val * s_zinv[h];
                        float posT = -__logf(1.f + (MPN + EPS_C) / v);
                        float negT = -__logf(1.f + (v + EPS_C) * (1.f / MPN));
                        corr += posT - negT;
                    }
                }
            }
        }
        for (int off = 32; off > 0; off >>= 1)
            corr += __shfl_down(corr, off, 64);
        __shared__ float s_c[4];
        if ((tid & 63) == 0) s_c[wv] = corr;
        __syncthreads();
        if (tid == 0)
            atomicAdd(out, -(s_c[0] + s_c[1] + s_c[2] + s_c[3]) / (float)BN);
    }
}

// ---------------------------------------------------------------------------
// fp32 fallback pieces (only if workspace too small for the full path)
// ---------------------------------------------------------------------------
__global__ void k_feat(const float* __restrict__ e0, const float* __restrict__ e1,
                       const float* __restrict__ e2, const float* __restrict__ e3,
                       const float* __restrict__ W, const float* __restrict__ bias,
                       float* __restrict__ e_out) {
    const int r = blockIdx.x;
    const int b = blockIdx.y;
    const float* emb = (r == 0 ? e0 : r == 1 ? e1 : r == 2 ? e2 : e3) + (size_t)b * REP;

    __shared__ float s_emb[REP];
    for (int i = threadIdx.x; i < REP; i += blockDim.x) s_emb[i] = emb[i];
    __syncthreads();

    const int d = threadIdx.x;
    const float4* wrow = (const float4*)(W + ((size_t)r * FD + d) * REP);
    float acc = 0.f;
#pragma unroll 8
    for (int c = 0; c < REP / 4; ++c) {
        float4 v = wrow[c];
        acc += v.x * s_emb[4*c+0] + v.y * s_emb[4*c+1]
             + v.z * s_emb[4*c+2] + v.w * s_emb[4*c+3];
    }
    float h = acc + bias[r * FD + d];

    __shared__ float red[FD];
    red[d] = h * h;
    __syncthreads();
    for (int off = FD / 2; off > 0; off >>= 1) {
        if (d < off) red[d] += red[d + off];
        __syncthreads();
    }
    float nrm = sqrtf(red[0]);
    e_out[((size_t)r * BN + b) * FD + d] = h / nrm;
}

static __device__ __forceinline__ void dot4(const float4* __restrict__ row,
                                            const float* __restrict__ se,
                                            float& a0, float& a1, float& a2, float& a3) {
    a0 = a1 = a2 = a3 = 0.f;
#pragma unroll 8
    for (int c = 0; c < FD / 4; ++c) {
        float4 v = row[c];
        const int o = 4 * c;
        a0 += v.x * se[0*FD+o+0] + v.y * se[0*FD+o+1] + v.z * se[0*FD+o+2] + v.w * se[0*FD+o+3];
        a1 += v.x * se[1*FD+o+0] + v.y * se[1*FD+o+1] + v.z * se[1*FD+o+2] + v.w * se[1*FD+o+3];
        a2 += v.x * se[2*FD+o+0] + v.y * se[2*FD+o+1] + v.z * se[2*FD+o+2] + v.w * se[2*FD+o+3];
        a3 += v.x * se[3*FD+o+0] + v.y * se[3*FD+o+1] + v.z * se[3*FD+o+2] + v.w * se[3*FD+o+3];
    }
}

static __device__ __forceinline__ void block_reduce4(float z0, float z1, float z2,
                                                     float z3, float* dst, int j) {
    __shared__ float sred[256];
    float zs[NBR] = {z0, z1, z2, z3};
    for (int i = 0; i < NBR; ++i) {
        sred[threadIdx.x] = zs[i];
        __syncthreads();
        for (int off = 128; off > 0; off >>= 1) {
            if ((int)threadIdx.x < off) sred[threadIdx.x] += sred[threadIdx.x + off];
            __syncthreads();
        }
        if (threadIdx.x == 0) atomicAdd(&dst[i * NBR + j], sred[0]);
        __syncthreads();
    }
}

static __device__ __forceinline__ float term_of(float ex, float zinv, int k) {
    const float c = MPN + EPS_C;
    float v = ex * zinv;
    if (k == 0) return -__logf(1.0f + c / v);
    return -__logf(1.0f + (v + EPS_C) * (1.0f / MPN));
}

template <bool STORE>
__global__ void k_pass1_f32(const float* __restrict__ e, const float* __restrict__ memory,
                            const int* __restrict__ cidx,
                            float* __restrict__ Zsum, ushort4* __restrict__ expS) {
    const int j = blockIdx.z;
    const int b = blockIdx.y;

    __shared__ float s_e[NBR * FD];
    for (int t = threadIdx.x; t < NBR * FD; t += blockDim.x) {
        int i = t >> 7, d = t & (FD - 1);
        s_e[t] = e[((size_t)i * BN + b) * FD + d];
    }
    __syncthreads();

    const int* ci = cidx + (size_t)b * KP1;
    const float4* mem4 = (const float4*)(memory + (size_t)j * NDATA * FD);
    float z0 = 0.f, z1 = 0.f, z2 = 0.f, z3 = 0.f;

    for (int k = threadIdx.x + blockIdx.x * blockDim.x; k < KP1;
         k += blockDim.x * gridDim.x) {
        const int n = ci[k];
        const float4* row = mem4 + (size_t)n * (FD / 4);
        float a0, a1, a2, a3;
        dot4(row, s_e, a0, a1, a2, a3);
        float x0 = __expf(a0 * TINV);
        float x1 = __expf(a1 * TINV);
        float x2 = __expf(a2 * TINV);
        float x3 = __expf(a3 * TINV);
        z0 += x0; z1 += x1; z2 += x2; z3 += x3;
        if (STORE) {
            ushort4 st;
            st.x = f2bf(x0); st.y = f2bf(x1); st.z = f2bf(x2); st.w = f2bf(x3);
            expS[((size_t)j * BN + b) * KP1 + k] = st;
        }
    }
    block_reduce4(z0, z1, z2, z3, Zsum, j);
}

__global__ void k_pass2_stored(const ushort4* __restrict__ expS,
                               const float* __restrict__ Zsum,
                               float* __restrict__ accum) {
    const int j = blockIdx.z;
    const int b = blockIdx.y;

    __shared__ float s_zinv[NBR];
    if (threadIdx.x < NBR) {
        float Z = Zsum[threadIdx.x * NBR + j] *
                  (float)((double)NDATA / ((double)BN * (double)KP1));
        s_zinv[threadIdx.x] = 1.0f / Z;
    }
    __syncthreads();

    const ushort4* es = expS + ((size_t)j * BN + b) * KP1;
    float a0 = 0.f, a1 = 0.f, a2 = 0.f, a3 = 0.f;

    for (int k = threadIdx.x + blockIdx.x * blockDim.x; k < KP1;
         k += blockDim.x * gridDim.x) {
        ushort4 v = es[k];
        a0 += term_of(bf2f(v.x), s_zinv[0], k);
        a1 += term_of(bf2f(v.y), s_zinv[1], k);
        a2 += term_of(bf2f(v.z), s_zinv[2], k);
        a3 += term_of(bf2f(v.w), s_zinv[3], k);
    }
    block_reduce4(a0, a1, a2, a3, accum, j);
}

__global__ void k_pass2_regather(const float* __restrict__ e, const float* __restrict__ memory,
                                 const int* __restrict__ cidx,
                                 const float* __restrict__ Zsum, float* __restrict__ accum) {
    const int j = blockIdx.z;
    const int b = blockIdx.y;

    __shared__ float s_e[NBR * FD];
    __shared__ float s_zinv[NBR];
    for (int t = threadIdx.x; t < NBR * FD; t += blockDim.x) {
        int i = t >> 7, d = t & (FD - 1);
        s_e[t] = e[((size_t)i * BN + b) * FD + d];
    }
    if (threadIdx.x < NBR) {
        float Z = Zsum[threadIdx.x * NBR + j] *
                  (float)((double)NDATA / ((double)BN * (double)KP1));
        s_zinv[threadIdx.x] = 1.0f / Z;
    }
    __syncthreads();

    const int* ci = cidx + (size_t)b * KP1;
    const float4* mem4 = (const float4*)(memory + (size_t)j * NDATA * FD);
    float a0s = 0.f, a1s = 0.f, a2s = 0.f, a3s = 0.f;

    for (int k = threadIdx.x + blockIdx.x * blockDim.x; k < KP1;
         k += blockDim.x * gridDim.x) {
        const int n = ci[k];
        const float4* row = mem4 + (size_t)n * (FD / 4);
        float a0, a1, a2, a3;
        dot4(row, s_e, a0, a1, a2, a3);
        a0s += term_of(__expf(a0 * TINV), s_zinv[0], k);
        a1s += term_of(__expf(a1 * TINV), s_zinv[1], k);
        a2s += term_of(__expf(a2 * TINV), s_zinv[2], k);
        a3s += term_of(__expf(a3 * TINV), s_zinv[3], k);
    }
    block_reduce4(a0s, a1s, a2s, a3s, accum, j);
}

__global__ void k_init(float* __restrict__ p, int n) {
    int i = blockIdx.x * blockDim.x + threadIdx.x;
    if (i < n) p[i] = 0.f;
}

__global__ void k_final_legacy(const float* __restrict__ accum, float* __restrict__ out) {
    if (threadIdx.x == 0) {
        float s = 0.f;
        for (int i = 0; i < NBR; ++i)
            for (int j = 0; j < NBR; ++j)
                if (i != j) s += -accum[i * NBR + j] / (float)BN;
        out[0] = s;
    }
}

// ---------------------------------------------------------------------------
extern "C" void kernel_launch(void* const* d_in, const int* in_sizes, int n_in,
                              void* d_out, int out_size, void* d_ws, size_t ws_size,
                              hipStream_t stream) {
    const float* e0   = (const float*)d_in[0];
    const float* e1   = (const float*)d_in[1];
    const float* e2   = (const float*)d_in[2];
    const float* e3   = (const float*)d_in[3];
    const float* W    = (const float*)d_in[4];
    const float* bias = (const float*)d_in[5];
    const float* mem  = (const float*)d_in[6];
    const int*   cidx = (const int*)d_in[8];
    float* out = (float*)d_out;

    float* ws    = (float*)d_ws;
    float* e     = ws;
    float* Zsum  = ws + 65536;
    float* accum = ws + 65552;
    float* Zsl   = ws + 65568;
    const size_t base_b  = (size_t)67616 * 4;               // 270,464 B
    const size_t cnt_b   = (size_t)NDATA * 4;               // 400,000 B
    const size_t inv_b   = (size_t)TREFS * 8;               // 4,195,328 B
    const size_t expS_b  = (size_t)TREFS * 16 * 2;          // 16,781,312 B
    const size_t eh2_b   = (size_t)BN * 16 * 4 * 8 * 2;     // 131,072 B

    const size_t off_counts = base_b;
    const size_t off_fill   = off_counts + cnt_b;
    const size_t off_cursor = off_fill + cnt_b;
    const size_t off_start  = off_cursor + 16;
    const size_t off_inv    = off_start + cnt_b;
    const size_t off_expS   = off_inv + inv_b;
    const size_t off_eh2    = off_expS + expS_b;
    const size_t off_posc   = off_eh2 + eh2_b;

    const size_t need_main = off_posc + 512;                // ~22.7 MB
    const size_t need_mid  = base_b + expS_b;               // ~17.05 MB

    if (ws_size >= need_main) {
        int* counts  = (int*)((char*)d_ws + off_counts);
        int* fill    = (int*)((char*)d_ws + off_fill);
        int* cursor  = (int*)((char*)d_ws + off_cursor);
        int* start   = (int*)((char*)d_ws + off_start);
        unsigned long long* inv64 = (unsigned long long*)((char*)d_ws + off_inv);
        ushort* expS = (ushort*)((char*)d_ws + off_expS);
        ushort* eh2  = (ushort*)((char*)d_ws + off_eh2);
        int* posc    = (int*)((char*)d_ws + off_posc);

        k_init2<<<782, 256, 0, stream>>>(counts, Zsl, out);
        k_fh<<<NBR * BN + 256, 256, 0, stream>>>(e0, e1, e2, e3, W, bias, cidx,
                                                 eh2, counts);
        k_assign<<<391, 256, 0, stream>>>(counts, start, cursor);
        k_scatter<<<dim3(17, BN), 256, 0, stream>>>(cidx, start, fill, inv64, posc);
        (void)hipGetLastError();   // clear any stale error
        k_pass1L<<<256, 1024, 131072, stream>>>(mem, eh2, inv64, Zsl, expS);
        if (hipGetLastError() != hipSuccess) {
            // 128 KB dynamic LDS rejected -> global-e fallback
            k_pass1i<<<2048, 256, 0, stream>>>(mem, eh2, inv64, Zsl, expS);
        }
        k_pass2s<<<1024, 256, 0, stream>>>((const uint4*)expS, Zsl, posc, out);
    } else {
        k_init<<<9, 256, 0, stream>>>(Zsum, 2080);
        k_feat<<<dim3(NBR, BN), 128, 0, stream>>>(e0, e1, e2, e3, W, bias, e);
        if (ws_size >= need_mid) {
            ushort4* expS = (ushort4*)((char*)d_ws + base_b);
            k_pass1_f32<true><<<dim3(4, BN, NBR), 256, 0, stream>>>(e, mem, cidx, Zsum, expS);
            k_pass2_stored<<<dim3(4, BN, NBR), 256, 0, stream>>>(expS, Zsum, accum);
        } else {
            k_pass1_f32<false><<<dim3(4, BN, NBR), 256, 0, stream>>>(e, mem, cidx, Zsum, nullptr);
            k_pass2_regather<<<dim3(4, BN, NBR), 256, 0, stream>>>(e, mem, cidx, Zsum, accum);
        }
        k_final_legacy<<<1, 64, 0, stream>>>(accum, out);
    }
}